// Round 9
// baseline (130.909 us; speedup 1.0000x reference)
//
#include <hip/hip_runtime.h>

#define BB 8
#define NN 128
#define ND 64
#define LL 512
#define RD 1024
#define CG 128
#define CP 128
#define HID 192
#define LDT 136

typedef __attribute__((ext_vector_type(8))) short short8;
typedef __attribute__((ext_vector_type(4))) float f32x4;

__device__ __forceinline__ unsigned short f2bf(float x) {
    unsigned u = __builtin_bit_cast(unsigned, x);
    u += 0x7fffu + ((u >> 16) & 1u);          // RNE
    return (unsigned short)(u >> 16);
}

// ---------------------------------------------------------------------------
// KFRONT, grid 1161 x 512 (71KB LDS -> 2 blocks/CU):
//  blk <1024  : protb = bf16(prot), 4096 elems/block
//  1024..1151 : WcT[c][k] = bf16((Wr@W1b)[k][c]), 8 k-rows/block
//  1152       : vbuf = W2@Wo ; cconst ; acc=0 ; ctr=0
//  1153..1160 : SELF-SUFFICIENT per-batch GNN: deg/norm, adjb, WgT, W1tT,
//               b1c, h0 (MFMA, inline bf16), 3 GNN steps (MFMA), hW1.
//               Only in-block syncs; global staging is same-block RW.
// ---------------------------------------------------------------------------
__global__ __launch_bounds__(512) void kfront(
    const float* __restrict__ adj, const float* __restrict__ nodes,
    const float* __restrict__ prot,
    const float* __restrict__ Wn, const float* __restrict__ bn,
    const float* __restrict__ Wr, const float* __restrict__ br,
    const float* __restrict__ W1, const float* __restrict__ b1,
    const float* __restrict__ Wg, const float* __restrict__ bg,
    const float* __restrict__ W2, const float* __restrict__ b2,
    const float* __restrict__ Wo, const float* __restrict__ bo,
    float* __restrict__ vbuf, float* __restrict__ cconst,
    float* __restrict__ acc, unsigned* __restrict__ ctr,
    unsigned short* __restrict__ protb, unsigned short* __restrict__ WcT,
    unsigned short* adjb, unsigned short* WgTg, unsigned short* W1tTg,
    float* __restrict__ hW1)
{
    __shared__ unsigned short hsT[NN][LDT];   // h*norm transposed [j][k], 34.8KB
    __shared__ unsigned short msb[NN][LDT];   // m*norm / tanh-h [i][j], 34.8KB
    __shared__ float snorm[NN];
    __shared__ float b1cL[HID];
    int t = threadIdx.x;
    int blk = blockIdx.x;

    if (blk < 1024) {
        size_t base = ((size_t)blk * 512 + t) * 8;
        float4 p0 = *(const float4*)(prot + base);
        float4 p1 = *(const float4*)(prot + base + 4);
        unsigned short o[8];
        o[0] = f2bf(p0.x); o[1] = f2bf(p0.y); o[2] = f2bf(p0.z); o[3] = f2bf(p0.w);
        o[4] = f2bf(p1.x); o[5] = f2bf(p1.y); o[6] = f2bf(p1.z); o[7] = f2bf(p1.w);
        *(short8*)(protb + base) = *(const short8*)o;
        return;
    }
    if (blk < 1152) {
        // WcT: 8 rows of Wc = Wr @ W1b, stored transposed bf16
        int r0 = (blk - 1024) * 8;
        float* sW = (float*)&hsT[0][0];       // 8x128 f32 scratch
        #pragma unroll
        for (int q = 0; q < 2; ++q) {
            int e = t + 512 * q;              // 0..1023
            sW[e] = Wr[(size_t)r0 * CG + e];
        }
        __syncthreads();
        #pragma unroll
        for (int q = 0; q < 3; ++q) {
            int o = t + 512 * q;              // 0..1535
            int r = o / HID, c = o % HID;
            float s = 0.f;
            for (int m = 0; m < CG; ++m)
                s = fmaf(sW[r * CG + m], W1[(size_t)(CG + m) * HID + c], s);
            WcT[(size_t)c * RD + r0 + r] = f2bf(s);
        }
        return;
    }
    if (blk == 1152) {
        if (t < HID) {
            float s = 0.f;
            for (int k = 0; k < CG; ++k) s = fmaf(W2[t * CG + k], Wo[k], s);
            vbuf[t] = s;
        }
        if (t == 255) {
            float s = 0.f;
            for (int k = 0; k < CG; ++k) s = fmaf(b2[k], Wo[k], s);
            cconst[0] = (float)(NN * LL) * s + bo[0];
        }
        if (t == 254) *ctr = 0u;
        if (t < BB) acc[t] = 0.f;
        return;
    }

    // ---------------- GNN block, batch b ----------------
    int b = blk - 1153;
    int w = t >> 6, l = t & 63;
    int lr = l & 15;
    int ks = l >> 4;
    int lk = ks * 8;
    int i0 = w * 16;

    // P0: deg+adjb (t<128) | b1c (128..319) | WgT,W1tT transposes (320..511)
    if (t < NN) {
        const float* ar = adj + ((size_t)b * NN + t) * NN;
        unsigned short* abr = adjb + ((size_t)b * NN + t) * NN;
        float d = 0.f;
        #pragma unroll
        for (int c8 = 0; c8 < 16; ++c8) {
            float4 p0 = *(const float4*)(ar + c8 * 8);
            float4 p1 = *(const float4*)(ar + c8 * 8 + 4);
            d += ((p0.x + p0.y) + (p0.z + p0.w)) + ((p1.x + p1.y) + (p1.z + p1.w));
            unsigned short o[8];
            o[0] = f2bf(p0.x); o[1] = f2bf(p0.y); o[2] = f2bf(p0.z); o[3] = f2bf(p0.w);
            o[4] = f2bf(p1.x); o[5] = f2bf(p1.y); o[6] = f2bf(p1.z); o[7] = f2bf(p1.w);
            *(short8*)(abr + c8 * 8) = *(const short8*)o;
        }
        snorm[t] = rsqrtf(fmaxf(d, 1.0f));
    } else if (t < 320) {
        int jj = t - 128;
        float s = b1[jj];
        for (int m = 0; m < CG; ++m)
            s = fmaf(br[m], W1[(size_t)(CG + m) * HID + jj], s);
        b1cL[jj] = s;
    } else {
        for (int e = t - 320; e < CG * CG; e += 192) {
            int c = e >> 7, j = e & 127;
            WgTg[e] = f2bf(Wg[j * CG + c]);
        }
        for (int e = t - 320; e < HID * CG; e += 192) {
            int jj = e >> 7, k = e & 127;
            W1tTg[e] = f2bf(W1[(size_t)k * HID + jj]);
        }
    }
    __syncthreads();

    // P1: h0 = nodes@Wn + bn via MFMA (inline bf16), -> hsT[j][k] scaled
    {
        short8 anod[2];
        #pragma unroll
        for (int kk = 0; kk < 2; ++kk) {
            const float* np = nodes + ((size_t)b * NN + i0 + lr) * ND + kk * 32 + lk;
            float4 q0 = *(const float4*)(np);
            float4 q1 = *(const float4*)(np + 4);
            unsigned short u[8];
            u[0] = f2bf(q0.x); u[1] = f2bf(q0.y); u[2] = f2bf(q0.z); u[3] = f2bf(q0.w);
            u[4] = f2bf(q1.x); u[5] = f2bf(q1.y); u[6] = f2bf(q1.z); u[7] = f2bf(q1.w);
            anod[kk] = *(const short8*)u;
        }
        #pragma unroll
        for (int ct = 0; ct < 8; ++ct) {
            int j = ct * 16 + lr;
            f32x4 d = {0.f, 0.f, 0.f, 0.f};
            #pragma unroll
            for (int kk = 0; kk < 2; ++kk) {
                unsigned short u[8];
                #pragma unroll
                for (int q = 0; q < 8; ++q)
                    u[q] = f2bf(Wn[(size_t)(kk * 32 + lk + q) * CG + j]);
                d = __builtin_amdgcn_mfma_f32_16x16x32_bf16(anod[kk], *(const short8*)u, d, 0, 0, 0);
            }
            float bnv = bn[j];
            #pragma unroll
            for (int i = 0; i < 4; ++i) {
                int r = i0 + ks * 4 + i;
                hsT[j][r] = f2bf((d[i] + bnv) * snorm[r]);
            }
        }
    }
    __syncthreads();

    // P2: 3 GNN steps via MFMA (adjb/WgT global same-block staging)
    for (int s = 0; s < 3; ++s) {
        short8 af[4];
        #pragma unroll
        for (int kk = 0; kk < 4; ++kk)
            af[kk] = *(const short8*)(adjb + ((size_t)b * NN + i0 + lr) * NN + kk * 32 + lk);
        #pragma unroll
        for (int jt = 0; jt < 8; ++jt) {
            int j0 = jt * 16;
            f32x4 d = {0.f, 0.f, 0.f, 0.f};
            #pragma unroll
            for (int kk = 0; kk < 4; ++kk) {
                short8 bf = *(const short8*)(&hsT[j0 + lr][kk * 32 + lk]);
                d = __builtin_amdgcn_mfma_f32_16x16x32_bf16(af[kk], bf, d, 0, 0, 0);
            }
            #pragma unroll
            for (int i = 0; i < 4; ++i) {
                int ii = i0 + ks * 4 + i;
                msb[ii][j0 + lr] = f2bf(d[i] * snorm[ii]);
            }
        }
        __syncthreads();
        unsigned short tp[8][4];
        #pragma unroll
        for (int ct = 0; ct < 8; ++ct) {
            int c0 = ct * 16;
            f32x4 d = {0.f, 0.f, 0.f, 0.f};
            #pragma unroll
            for (int kk = 0; kk < 4; ++kk) {
                short8 afm = *(const short8*)(&msb[i0 + lr][kk * 32 + lk]);
                short8 bfw = *(const short8*)(WgTg + (size_t)(c0 + lr) * CG + kk * 32 + lk);
                d = __builtin_amdgcn_mfma_f32_16x16x32_bf16(afm, bfw, d, 0, 0, 0);
            }
            float bgv = bg[c0 + lr];
            if (s < 2) {
                unsigned short p[4];
                #pragma unroll
                for (int i = 0; i < 4; ++i) {
                    int ii = i0 + ks * 4 + i;
                    p[i] = f2bf(fmaxf(d[i] + bgv, 0.f) * snorm[ii]);
                }
                *(uint2*)(&hsT[c0 + lr][i0 + ks * 4]) = *(uint2*)p;
            } else {
                #pragma unroll
                for (int i = 0; i < 4; ++i)
                    tp[ct][i] = f2bf(tanhf(d[i] + bgv));
            }
        }
        if (s < 2) {
            __syncthreads();
        } else {
            #pragma unroll
            for (int ct = 0; ct < 8; ++ct)
                #pragma unroll
                for (int i = 0; i < 4; ++i)
                    msb[i0 + ks * 4 + i][ct * 16 + lr] = tp[ct][i];
        }
    }

    // hW1 = tanh-h @ W1_top + b1c
    short8 ah[4];
    #pragma unroll
    for (int kk = 0; kk < 4; ++kk)
        ah[kk] = *(const short8*)(&msb[i0 + lr][kk * 32 + lk]);
    #pragma unroll
    for (int jjt = 0; jjt < 12; ++jjt) {
        int jj0 = jjt * 16;
        f32x4 d = {0.f, 0.f, 0.f, 0.f};
        #pragma unroll
        for (int kk = 0; kk < 4; ++kk) {
            short8 bfw = *(const short8*)(W1tTg + (size_t)(jj0 + lr) * CG + kk * 32 + lk);
            d = __builtin_amdgcn_mfma_f32_16x16x32_bf16(ah[kk], bfw, d, 0, 0, 0);
        }
        float bv = b1cL[jj0 + lr];
        #pragma unroll
        for (int i = 0; i < 4; ++i)
            hW1[((size_t)b * NN + i0 + ks * 4 + i) * HID + jj0 + lr] = d[i] + bv;
    }
}

// ---------------------------------------------------------------------------
// KBACK, grid 256 x 512 (1 block/CU): full-K GEMM tile (64 l-rows x 96 j-cols)
// kept in registers + fused pairsum epilogue over an n-half. rW never hits
// memory. idx = nh(2) x jb(2) x rb(64). Last block adds cconst -> out.
// ---------------------------------------------------------------------------
__global__ __launch_bounds__(512) void kback(
    const unsigned short* __restrict__ protb, const unsigned short* __restrict__ WcT,
    const float* __restrict__ hW1, const float* __restrict__ vbuf,
    float* __restrict__ acc, const float* __restrict__ cconst,
    unsigned* __restrict__ ctr, float* __restrict__ out)
{
    int t = threadIdx.x;
    int idx = blockIdx.x;
    int nh = idx & 1;
    int jb = (idx >> 1) & 1;
    int rb = idx >> 2;              // 0..63
    int w = t >> 6, l = t & 63;
    int wr = w & 3, wc = w >> 2;
    int lr = l & 15;
    int lk = (l >> 4) * 8;
    int r0 = rb * 64 + wr * 16;
    int c0 = jb * 96 + wc * 48;
    int b = rb >> 3;
    const unsigned short* ap = protb + (size_t)(r0 + lr) * RD + lk;
    const unsigned short* bp = WcT + (size_t)(c0 + lr) * RD + lk;
    f32x4 a0 = {0.f, 0.f, 0.f, 0.f}, a1 = a0, a2 = a0;
    #pragma unroll 4
    for (int k0 = 0; k0 < RD; k0 += 32) {
        short8 av = *(const short8*)(ap + k0);
        short8 b0 = *(const short8*)(bp + k0);
        short8 b1 = *(const short8*)(bp + 16 * RD + k0);
        short8 b2 = *(const short8*)(bp + 32 * RD + k0);
        a0 = __builtin_amdgcn_mfma_f32_16x16x32_bf16(av, b0, a0, 0, 0, 0);
        a1 = __builtin_amdgcn_mfma_f32_16x16x32_bf16(av, b1, a1, 0, 0, 0);
        a2 = __builtin_amdgcn_mfma_f32_16x16x32_bf16(av, b2, a2, 0, 0, 0);
    }
    // fused pairsum epilogue over n-half
    int j0 = c0 + lr;
    float v0 = vbuf[j0], v1 = vbuf[j0 + 16], v2 = vbuf[j0 + 32];
    const float* hp = hW1 + ((size_t)b * NN + nh * 64) * HID;
    float s = 0.f;
    #pragma unroll 4
    for (int n = 0; n < 64; ++n) {
        float h0 = hp[n * HID + j0];
        float h1 = hp[n * HID + j0 + 16];
        float h2 = hp[n * HID + j0 + 32];
        #pragma unroll
        for (int i = 0; i < 4; ++i) {
            s = fmaf(v0, fmaxf(a0[i] + h0, 0.f), s);
            s = fmaf(v1, fmaxf(a1[i] + h1, 0.f), s);
            s = fmaf(v2, fmaxf(a2[i] + h2, 0.f), s);
        }
    }
    for (int off = 32; off; off >>= 1) s += __shfl_down(s, off);
    __shared__ float sred[8];
    __shared__ int lastf;
    if (l == 0) sred[w] = s;
    __syncthreads();
    if (t == 0) {
        float tot = ((sred[0] + sred[1]) + (sred[2] + sred[3]))
                  + ((sred[4] + sred[5]) + (sred[6] + sred[7]));
        atomicAdd(&acc[b], tot);
        __threadfence();
        unsigned old = atomicAdd(ctr, 1u);
        lastf = (old == gridDim.x - 1) ? 1 : 0;
    }
    __syncthreads();
    if (lastf && t < BB)
        out[t] = atomicAdd(&acc[t], 0.0f) + cconst[0];
}

extern "C" void kernel_launch(void* const* d_in, const int* in_sizes, int n_in,
                              void* d_out, int out_size, void* d_ws, size_t ws_size,
                              hipStream_t stream)
{
    const float* adj   = (const float*)d_in[0];
    const float* nodes = (const float*)d_in[1];
    const float* prot  = (const float*)d_in[2];
    const float* Wn    = (const float*)d_in[3];
    const float* bn    = (const float*)d_in[4];
    const float* Wg    = (const float*)d_in[5];
    const float* bg    = (const float*)d_in[6];
    const float* Wr    = (const float*)d_in[7];
    const float* br    = (const float*)d_in[8];
    // d_in[9]=Wa, d_in[10]=ba: unused (softmax over size-1 axis == 1)
    const float* W1    = (const float*)d_in[11];
    const float* b1    = (const float*)d_in[12];
    const float* W2    = (const float*)d_in[13];
    const float* b2    = (const float*)d_in[14];
    const float* Wo    = (const float*)d_in[15];
    const float* bo    = (const float*)d_in[16];

    float* ws     = (float*)d_ws;
    float* hW1b   = ws;                        // [8][128][192] = 196608
    float* vbuf   = ws + 196608;               // [192]
    float* cconst = ws + 196800;               // [1]
    float* accb   = ws + 196804;               // [8]
    unsigned* ctr = (unsigned*)(ws + 196812);  // [1]
    unsigned short* adjb  = (unsigned short*)(ws + 196816); // [8][128][128] bf16
    unsigned short* WgTg  = (unsigned short*)(ws + 262352); // [128][128] bf16
    unsigned short* W1tTg = (unsigned short*)(ws + 270544); // [192][128] bf16
    unsigned short* protb = (unsigned short*)(ws + 282832); // [4096][1024] bf16
    unsigned short* WcT   = (unsigned short*)(ws + 2379984);// [192][1024] bf16
    float* out    = (float*)d_out;

    hipLaunchKernelGGL(kfront, dim3(1161), dim3(512), 0, stream,
                       adj, nodes, prot, Wn, bn, Wr, br, W1, b1, Wg, bg,
                       W2, b2, Wo, bo, vbuf, cconst, accb, ctr,
                       protb, WcT, adjb, WgTg, W1tTg, hW1b);
    hipLaunchKernelGGL(kback, dim3(256), dim3(512), 0, stream,
                       protb, WcT, hW1b, vbuf, accb, cconst, ctr, out);
}

// Round 10
// 91.370 us; speedup vs baseline: 1.4327x; 1.4327x over previous
//
#include <hip/hip_runtime.h>

#define BB 8
#define NN 128
#define ND 64
#define LL 512
#define RD 1024
#define CG 128
#define CP 128
#define HID 192
#define LDT 136

typedef __attribute__((ext_vector_type(8))) short short8;
typedef __attribute__((ext_vector_type(4))) float f32x4;

__device__ __forceinline__ unsigned short f2bf(float x) {
    unsigned u = __builtin_bit_cast(unsigned, x);
    u += 0x7fffu + ((u >> 16) & 1u);          // RNE
    return (unsigned short)(u >> 16);
}

// ---------------------------------------------------------------------------
// K1 (grid 2563 x 256)  [R8-verified structure]:
//  blk <256   : h0 = nodes@Wn + bn (f32) ; norm ; adjb = bf16(adj)
//  blk ==256  : vbuf = W2@Wo ; b1c = b1 + br@W1b ; cconst ; acc=0; ctr=0
//  257..512   : WcT[c][k] = bf16( (Wr@W1b)[k][c] )
//  513        : WgT ; 514 : W1tT ; 515..2562 : protb = bf16(prot)
// ---------------------------------------------------------------------------
__global__ __launch_bounds__(256) void k1_prep(
    const float* __restrict__ adj, const float* __restrict__ nodes,
    const float* __restrict__ prot,
    const float* __restrict__ Wn, const float* __restrict__ bn,
    const float* __restrict__ Wr, const float* __restrict__ br,
    const float* __restrict__ W1, const float* __restrict__ b1,
    const float* __restrict__ Wg,
    const float* __restrict__ W2, const float* __restrict__ b2,
    const float* __restrict__ Wo, const float* __restrict__ bo,
    float* __restrict__ hA, float* __restrict__ normb,
    float* __restrict__ vbuf, float* __restrict__ cconst,
    float* __restrict__ acc, unsigned* __restrict__ ctr,
    unsigned short* __restrict__ WcT, float* __restrict__ b1c,
    unsigned short* __restrict__ protb, unsigned short* __restrict__ adjb,
    unsigned short* __restrict__ WgT, unsigned short* __restrict__ W1tT)
{
    int t = threadIdx.x;
    int blk = blockIdx.x;
    const float* W1b = W1 + CG * HID;
    if (blk >= 515) {
        size_t base = (size_t)(blk - 515) * 2048 + (size_t)t * 8;
        float4 p0 = *(const float4*)(prot + base);
        float4 p1 = *(const float4*)(prot + base + 4);
        unsigned short o[8];
        o[0] = f2bf(p0.x); o[1] = f2bf(p0.y); o[2] = f2bf(p0.z); o[3] = f2bf(p0.w);
        o[4] = f2bf(p1.x); o[5] = f2bf(p1.y); o[6] = f2bf(p1.z); o[7] = f2bf(p1.w);
        *(short8*)(protb + base) = *(const short8*)o;
        return;
    }
    if (blk == 514) {
        #pragma unroll
        for (int q = 0; q < 96; ++q) {
            int e = t + 256 * q;            // 0..24575
            int jj = e >> 7, k = e & 127;
            W1tT[e] = f2bf(W1[k * HID + jj]);
        }
        return;
    }
    if (blk == 513) {
        #pragma unroll
        for (int q = 0; q < 64; ++q) {
            int e = t + 256 * q;            // 0..16383
            int c = e >> 7, j = e & 127;
            WgT[e] = f2bf(Wg[j * CG + c]);
        }
        return;
    }
    if (blk == 256) {
        if (t < HID) {
            float s = 0.f;
            for (int k = 0; k < CG; ++k) s = fmaf(W2[t * CG + k], Wo[k], s);
            vbuf[t] = s;
            float sb = 0.f;
            for (int m = 0; m < CG; ++m) sb = fmaf(br[m], W1b[m * HID + t], sb);
            b1c[t] = b1[t] + sb;
        }
        if (t == 255) {
            float s = 0.f;
            for (int k = 0; k < CG; ++k) s = fmaf(b2[k], Wo[k], s);
            cconst[0] = (float)(NN * LL) * s + bo[0];
        }
        if (t == 254) *ctr = 0u;
        if (t < BB) acc[t] = 0.f;
        return;
    }
    if (blk > 256) {
        int r0 = (blk - 257) * 4;
        __shared__ float sW[4][CG];
        if (t < 128) ((float4*)&sW[0][0])[t] = ((const float4*)(Wr + (size_t)r0 * CG))[t];
        __syncthreads();
        #pragma unroll
        for (int q = 0; q < 3; ++q) {
            int o = q * 256 + t;            // 0..767
            int r = o / HID, c = o % HID;
            float s = 0.f;
            for (int m = 0; m < CG; ++m) s = fmaf(sW[r][m], W1b[m * HID + c], s);
            WcT[(size_t)c * RD + r0 + r] = f2bf(s);
        }
        return;
    }
    int b = blk >> 5;           // 32 blocks per batch
    int n0 = (blk & 31) * 4;    // 4 rows per block
    __shared__ float sn[4][ND];
    sn[t >> 6][t & 63] = nodes[(b * NN + n0 + (t >> 6)) * ND + (t & 63)];
    __syncthreads();
    {
        int w = t >> 6, lane = t & 63;
        const float* ar = adj + (size_t)(b * NN + n0 + w) * NN;
        float d = ar[lane] + ar[lane + 64];
        for (int off = 32; off; off >>= 1) d += __shfl_down(d, off);
        if (lane == 0) normb[b * NN + n0 + w] = rsqrtf(fmaxf(d, 1.0f));
    }
    #pragma unroll
    for (int q = 0; q < 2; ++q) {
        int e = t + 256 * q;               // 0..511
        int row = e >> 7, col = e & 127;
        size_t ix = ((size_t)b * NN + n0 + row) * NN + col;
        adjb[ix] = f2bf(adj[ix]);
    }
    int c = t & 127, rr = t >> 7;   // rows rr and rr+2
    float a0 = bn[c], a1 = bn[c];
    for (int k = 0; k < ND; ++k) {
        float wv = Wn[k * CG + c];
        a0 = fmaf(sn[rr][k], wv, a0);
        a1 = fmaf(sn[rr + 2][k], wv, a1);
    }
    hA[(b * NN + n0 + rr) * CG + c] = a0;
    hA[(b * NN + n0 + rr + 2) * CG + c] = a1;
}

// ---------------------------------------------------------------------------
// KFUSE, grid 128 x 512 (2 waves/SIMD min):
//  block (cb, rblk): cb = 48-col group (4), rblk = 128-row l-chunk (32);
//  b = rblk/4, l0 = (rblk%4)*128.
//  1. redundant per-batch GNN (R8-verified MFMA code), tanh-h in msb
//  2. hW1 slice (48 cols) -> LDS f32 (reuses hsT region)
//  3. full-K GEMM tile (128 rows x 48 cols) in registers
//  4. fused pairsum epilogue; one atomicAdd per block; last block -> out
// ---------------------------------------------------------------------------
__global__ __launch_bounds__(512, 2) void kfuse(
    const unsigned short* __restrict__ protb, const unsigned short* __restrict__ WcT,
    const unsigned short* __restrict__ adjb, const unsigned short* __restrict__ WgTg,
    const unsigned short* __restrict__ W1tTg,
    const float* __restrict__ bg, const float* __restrict__ normb,
    const float* __restrict__ hA, const float* __restrict__ b1c,
    const float* __restrict__ vbuf, float* __restrict__ acc,
    const float* __restrict__ cconst, unsigned* __restrict__ ctr,
    float* __restrict__ out)
{
    __shared__ unsigned short hsT[NN][LDT];   // h*norm transposed; later hW1s f32
    __shared__ unsigned short msb[NN][LDT];   // m*norm / tanh-h
    __shared__ float snorm[NN];
    int t = threadIdx.x;
    int blk = blockIdx.x;
    int cb = blk & 3;
    int rblk = blk >> 2;            // 0..31
    int b = rblk >> 2;
    int l0 = (rblk & 3) * 128;
    int w = t >> 6, l = t & 63;
    int lr = l & 15;
    int ks = l >> 4;
    int lk = ks * 8;
    int i0 = w * 16;

    if (t < NN) snorm[t] = normb[b * NN + t];
    __syncthreads();
    // stage hsT[j][k] = bf16(hA[b][k][j] * norm[k])
    #pragma unroll
    for (int q = 0; q < 8; ++q) {
        int f4 = t + 512 * q;          // 0..4095
        int k = f4 >> 5;               // 0..127
        int j0 = (f4 & 31) * 4;
        float4 hv = *(const float4*)(hA + ((size_t)b * NN + k) * CG + j0);
        float nv = snorm[k];
        hsT[j0 + 0][k] = f2bf(hv.x * nv);
        hsT[j0 + 1][k] = f2bf(hv.y * nv);
        hsT[j0 + 2][k] = f2bf(hv.z * nv);
        hsT[j0 + 3][k] = f2bf(hv.w * nv);
    }
    __syncthreads();

    // 3 GNN steps via MFMA (R8-verified)
    for (int s = 0; s < 3; ++s) {
        short8 af[4];
        #pragma unroll
        for (int kk = 0; kk < 4; ++kk)
            af[kk] = *(const short8*)(adjb + ((size_t)b * NN + i0 + lr) * NN + kk * 32 + lk);
        #pragma unroll
        for (int jt = 0; jt < 8; ++jt) {
            int j0 = jt * 16;
            f32x4 d = {0.f, 0.f, 0.f, 0.f};
            #pragma unroll
            for (int kk = 0; kk < 4; ++kk) {
                short8 bf = *(const short8*)(&hsT[j0 + lr][kk * 32 + lk]);
                d = __builtin_amdgcn_mfma_f32_16x16x32_bf16(af[kk], bf, d, 0, 0, 0);
            }
            #pragma unroll
            for (int i = 0; i < 4; ++i) {
                int ii = i0 + ks * 4 + i;
                msb[ii][j0 + lr] = f2bf(d[i] * snorm[ii]);
            }
        }
        __syncthreads();
        unsigned short tp[8][4];
        #pragma unroll
        for (int ct = 0; ct < 8; ++ct) {
            int c0 = ct * 16;
            f32x4 d = {0.f, 0.f, 0.f, 0.f};
            #pragma unroll
            for (int kk = 0; kk < 4; ++kk) {
                short8 afm = *(const short8*)(&msb[i0 + lr][kk * 32 + lk]);
                short8 bfw = *(const short8*)(WgTg + (size_t)(c0 + lr) * CG + kk * 32 + lk);
                d = __builtin_amdgcn_mfma_f32_16x16x32_bf16(afm, bfw, d, 0, 0, 0);
            }
            float bgv = bg[c0 + lr];
            if (s < 2) {
                unsigned short p[4];
                #pragma unroll
                for (int i = 0; i < 4; ++i) {
                    int ii = i0 + ks * 4 + i;
                    p[i] = f2bf(fmaxf(d[i] + bgv, 0.f) * snorm[ii]);
                }
                *(uint2*)(&hsT[c0 + lr][i0 + ks * 4]) = *(uint2*)p;
            } else {
                #pragma unroll
                for (int i = 0; i < 4; ++i)
                    tp[ct][i] = f2bf(tanhf(d[i] + bgv));
            }
        }
        if (s < 2) {
            __syncthreads();
        } else {
            #pragma unroll
            for (int ct = 0; ct < 8; ++ct)
                #pragma unroll
                for (int i = 0; i < 4; ++i)
                    msb[i0 + ks * 4 + i][ct * 16 + lr] = tp[ct][i];
        }
    }

    // hW1 slice (48 cols of this block) -> f32 LDS in hsT region [128][49]
    float* hW1s = (float*)&hsT[0][0];
    {
        short8 ah[4];
        #pragma unroll
        for (int kk = 0; kk < 4; ++kk)
            ah[kk] = *(const short8*)(&msb[i0 + lr][kk * 32 + lk]);
        #pragma unroll
        for (int ct = 0; ct < 3; ++ct) {
            int jc = cb * 48 + ct * 16 + lr;
            f32x4 d = {0.f, 0.f, 0.f, 0.f};
            #pragma unroll
            for (int kk = 0; kk < 4; ++kk) {
                short8 bfw = *(const short8*)(W1tTg + (size_t)jc * CG + kk * 32 + lk);
                d = __builtin_amdgcn_mfma_f32_16x16x32_bf16(ah[kk], bfw, d, 0, 0, 0);
            }
            float bv = b1c[jc];
            #pragma unroll
            for (int i = 0; i < 4; ++i)
                hW1s[(i0 + ks * 4 + i) * 49 + ct * 16 + lr] = d[i] + bv;
        }
    }
    __syncthreads();

    // full-K GEMM tile: wave w -> 16 rows (l0 + w*16), 48 cols (cb*48..)
    const unsigned short* ap = protb + (size_t)(b * LL + l0 + w * 16 + lr) * RD + lk;
    const unsigned short* bp = WcT + (size_t)(cb * 48 + lr) * RD + lk;
    f32x4 a0 = {0.f, 0.f, 0.f, 0.f}, a1 = a0, a2 = a0;
    #pragma unroll 4
    for (int k0 = 0; k0 < RD; k0 += 32) {
        short8 av = *(const short8*)(ap + k0);
        short8 b0 = *(const short8*)(bp + k0);
        short8 b1v = *(const short8*)(bp + 16 * RD + k0);
        short8 b2v = *(const short8*)(bp + 32 * RD + k0);
        a0 = __builtin_amdgcn_mfma_f32_16x16x32_bf16(av, b0, a0, 0, 0, 0);
        a1 = __builtin_amdgcn_mfma_f32_16x16x32_bf16(av, b1v, a1, 0, 0, 0);
        a2 = __builtin_amdgcn_mfma_f32_16x16x32_bf16(av, b2v, a2, 0, 0, 0);
    }

    // fused pairsum epilogue: sum_n v . relu(rW + hW1s[n])
    float v0 = vbuf[cb * 48 + lr];
    float v1 = vbuf[cb * 48 + 16 + lr];
    float v2 = vbuf[cb * 48 + 32 + lr];
    float s = 0.f;
    #pragma unroll 4
    for (int n = 0; n < NN; ++n) {
        float h0 = hW1s[n * 49 + lr];
        float h1 = hW1s[n * 49 + 16 + lr];
        float h2 = hW1s[n * 49 + 32 + lr];
        #pragma unroll
        for (int i = 0; i < 4; ++i) {
            s = fmaf(v0, fmaxf(a0[i] + h0, 0.f), s);
            s = fmaf(v1, fmaxf(a1[i] + h1, 0.f), s);
            s = fmaf(v2, fmaxf(a2[i] + h2, 0.f), s);
        }
    }
    for (int off = 32; off; off >>= 1) s += __shfl_down(s, off);
    __shared__ float sred[8];
    __shared__ int lastf;
    if (l == 0) sred[w] = s;
    __syncthreads();
    if (t == 0) {
        float tot = ((sred[0] + sred[1]) + (sred[2] + sred[3]))
                  + ((sred[4] + sred[5]) + (sred[6] + sred[7]));
        atomicAdd(&acc[b], tot);
        __threadfence();
        unsigned old = atomicAdd(ctr, 1u);
        lastf = (old == gridDim.x - 1) ? 1 : 0;
    }
    __syncthreads();
    if (lastf && t < BB)
        out[t] = atomicAdd(&acc[t], 0.0f) + cconst[0];
}

extern "C" void kernel_launch(void* const* d_in, const int* in_sizes, int n_in,
                              void* d_out, int out_size, void* d_ws, size_t ws_size,
                              hipStream_t stream)
{
    const float* adj   = (const float*)d_in[0];
    const float* nodes = (const float*)d_in[1];
    const float* prot  = (const float*)d_in[2];
    const float* Wn    = (const float*)d_in[3];
    const float* bn    = (const float*)d_in[4];
    const float* Wg    = (const float*)d_in[5];
    const float* bg    = (const float*)d_in[6];
    const float* Wr    = (const float*)d_in[7];
    const float* br    = (const float*)d_in[8];
    // d_in[9]=Wa, d_in[10]=ba: unused (softmax over size-1 axis == 1)
    const float* W1    = (const float*)d_in[11];
    const float* b1    = (const float*)d_in[12];
    const float* W2    = (const float*)d_in[13];
    const float* b2    = (const float*)d_in[14];
    const float* Wo    = (const float*)d_in[15];
    const float* bo    = (const float*)d_in[16];

    float* ws     = (float*)d_ws;
    float* hA     = ws;                        // [8][128][128]
    float* normb  = ws + 131072;               // [8][128]
    float* vbuf   = ws + 132096;               // [192]
    float* cconst = ws + 132288;               // [1]
    float* accb   = ws + 132292;               // [8]
    float* b1c    = ws + 132300;               // [192]
    unsigned* ctr = (unsigned*)(ws + 132492);  // [1]
    unsigned short* adjb  = (unsigned short*)(ws + 132496); // [8][128][128]
    unsigned short* WgTg  = (unsigned short*)(ws + 198032); // [128][128]
    unsigned short* W1tTg = (unsigned short*)(ws + 206224); // [192][128]
    unsigned short* protb = (unsigned short*)(ws + 218512); // [4096][1024]
    unsigned short* WcT   = (unsigned short*)(ws + 2315664);// [192][1024]
    float* out    = (float*)d_out;

    hipLaunchKernelGGL(k1_prep, dim3(2563), dim3(256), 0, stream,
                       adj, nodes, prot, Wn, bn, Wr, br, W1, b1, Wg, W2, b2, Wo, bo,
                       hA, normb, vbuf, cconst, accb, ctr, WcT, b1c, protb,
                       adjb, WgTg, W1tTg);
    hipLaunchKernelGGL(kfuse, dim3(128), dim3(512), 0, stream,
                       protb, WcT, adjb, WgTg, W1tTg, bg, normb, hA, b1c,
                       vbuf, accb, cconst, ctr, out);
}

// Round 11
// 71.828 us; speedup vs baseline: 1.8225x; 1.2721x over previous
//
#include <hip/hip_runtime.h>

#define BB 8
#define NN 128
#define ND 64
#define LL 512
#define RD 1024
#define CG 128
#define HID 192

typedef __attribute__((ext_vector_type(8))) short short8;
typedef __attribute__((ext_vector_type(4))) float f32x4;

__device__ __forceinline__ unsigned short f2bf(float x) {
    unsigned u = __builtin_bit_cast(unsigned, x);
    u += 0x7fffu + ((u >> 16) & 1u);          // RNE
    return (unsigned short)(u >> 16);
}
__device__ __forceinline__ float bf2f(unsigned short h) {
    unsigned u = ((unsigned)h) << 16;
    return __builtin_bit_cast(float, u);
}
#define MFMA __builtin_amdgcn_mfma_f32_16x16x32_bf16

// ---------------------------------------------------------------------------
// K_PREP, grid 73 x 512:
//  blk 0..63 : WcT[c][k] = bf16((Wr@W1b)[k][c]), 16 k-rows/block (VALU)
//  blk 64    : vbuf = W2@Wo ; cconst = N*L*(b2@Wo)+bo ; acc=0 ; ctr=0
//  blk 65..72: SELF-SUFFICIENT per-batch GNN, all-MFMA, orientation-
//              alternating layouts, norms folded into adjn (regs).
//              Writes hW1T[b][192][128] f32 (bias b1c included).
// ---------------------------------------------------------------------------
__global__ __launch_bounds__(512, 1) void k_prep(
    const float* __restrict__ adj, const float* __restrict__ nodes,
    const float* __restrict__ Wn, const float* __restrict__ bn,
    const float* __restrict__ Wr, const float* __restrict__ br,
    const float* __restrict__ W1, const float* __restrict__ b1,
    const float* __restrict__ Wg, const float* __restrict__ bg,
    const float* __restrict__ W2, const float* __restrict__ b2,
    const float* __restrict__ Wo, const float* __restrict__ bo,
    unsigned short* __restrict__ WcT, float* __restrict__ hW1T,
    float* __restrict__ vbuf, float* __restrict__ cconst,
    float* __restrict__ acc, unsigned* __restrict__ ctr)
{
    __shared__ unsigned short hT[NN][136];   // 34.8KB: h feature-major (later node-major)
    __shared__ unsigned short mbuf[NN][72];  // 18.4KB: one j-half of m (wave-private rows)
    __shared__ float snorm[NN];
    __shared__ float b1cL[HID];
    __shared__ float sbg[NN];
    int t = threadIdx.x, blk = blockIdx.x;
    const float* W1b = W1 + CG * HID;

    if (blk < 64) {
        // WcT rows r0..r0+15 (transposed bf16 of Wr@W1b)
        int r0 = blk * 16;
        float* sW = (float*)&hT[0][0];       // 16x128 f32 scratch
        for (int e = t; e < 16 * CG; e += 512) sW[e] = Wr[(size_t)r0 * CG + e];
        __syncthreads();
        for (int o = t; o < 16 * HID; o += 512) {
            int r = o / HID, c = o % HID;
            float s = 0.f;
            #pragma unroll 8
            for (int m = 0; m < CG; ++m)
                s = fmaf(sW[r * CG + m], W1b[(size_t)m * HID + c], s);
            WcT[(size_t)c * RD + r0 + r] = f2bf(s);
        }
        return;
    }
    if (blk == 64) {
        if (t < HID) {
            float s = 0.f;
            #pragma unroll 8
            for (int k = 0; k < CG; ++k) s = fmaf(W2[t * CG + k], Wo[k], s);
            vbuf[t] = s;
        }
        if (t == 511) {
            float s = 0.f;
            for (int k = 0; k < CG; ++k) s = fmaf(b2[k], Wo[k], s);
            cconst[0] = (float)(NN * LL) * s + bo[0];
        }
        if (t == 510) *ctr = 0u;
        if (t < BB) acc[t] = 0.f;
        return;
    }

    // ---------------- GNN block, batch b ----------------
    int b = blk - 65;
    int w = t >> 6, l = t & 63, lr = l & 15, ks = l >> 4, lk = ks * 8;
    int i0 = w * 16;                 // wave's 16-node tile (i/n dim)

    // P0: degrees -> snorm ; b1c ; stage bg
    {
        float* dscr = (float*)&mbuf[0][0];   // [128][4] f32
        int row = t >> 2, q4 = t & 3;
        const float* ar = adj + ((size_t)b * NN + row) * NN + q4 * 32;
        float d = 0.f;
        #pragma unroll
        for (int c4 = 0; c4 < 8; ++c4) {
            float4 p = *(const float4*)(ar + c4 * 4);
            d += (p.x + p.y) + (p.z + p.w);
        }
        dscr[row * 4 + q4] = d;
        __syncthreads();
        if (t < NN) {
            snorm[t] = rsqrtf(fmaxf(dscr[t*4] + dscr[t*4+1] + dscr[t*4+2] + dscr[t*4+3], 1.f));
        } else if (t < 320) {
            int j = t - 128;
            float s = b1[j];
            #pragma unroll 8
            for (int m = 0; m < CG; ++m)
                s = fmaf(br[m], W1b[(size_t)m * HID + j], s);
            b1cL[j] = s;
        } else if (t < 448) {
            sbg[t - 320] = bg[t - 320];
        }
        __syncthreads();
    }

    // adjn fragments in regs: adjn[i][k] = adj[i][k]*norm[i]*norm[k] (bf16)
    short8 af[4];
    {
        float ni = snorm[i0 + lr];
        const float* ar = adj + ((size_t)b * NN + i0 + lr) * NN;
        #pragma unroll
        for (int kk = 0; kk < 4; ++kk) {
            int kb = kk * 32 + lk;
            float4 p0 = *(const float4*)(ar + kb);
            float4 p1 = *(const float4*)(ar + kb + 4);
            unsigned short u[8];
            u[0] = f2bf(p0.x * ni * snorm[kb+0]); u[1] = f2bf(p0.y * ni * snorm[kb+1]);
            u[2] = f2bf(p0.z * ni * snorm[kb+2]); u[3] = f2bf(p0.w * ni * snorm[kb+3]);
            u[4] = f2bf(p1.x * ni * snorm[kb+4]); u[5] = f2bf(p1.y * ni * snorm[kb+5]);
            u[6] = f2bf(p1.z * ni * snorm[kb+6]); u[7] = f2bf(p1.w * ni * snorm[kb+7]);
            af[kk] = *(const short8*)u;
        }
    }

    // h0 = nodes@Wn + bn  ->  hT[c][n] feature-major (MFMA, inline cvt)
    {
        short8 bnod[2];
        #pragma unroll
        for (int kk = 0; kk < 2; ++kk) {
            const float* np = nodes + ((size_t)b * NN + i0 + lr) * ND + kk * 32 + lk;
            float4 q0 = *(const float4*)np;
            float4 q1 = *(const float4*)(np + 4);
            unsigned short u[8];
            u[0]=f2bf(q0.x); u[1]=f2bf(q0.y); u[2]=f2bf(q0.z); u[3]=f2bf(q0.w);
            u[4]=f2bf(q1.x); u[5]=f2bf(q1.y); u[6]=f2bf(q1.z); u[7]=f2bf(q1.w);
            bnod[kk] = *(const short8*)u;
        }
        #pragma unroll
        for (int ct = 0; ct < 8; ++ct) {
            f32x4 d = {0.f, 0.f, 0.f, 0.f};
            #pragma unroll
            for (int kk = 0; kk < 2; ++kk) {
                unsigned short u[8];
                #pragma unroll
                for (int q = 0; q < 8; ++q)
                    u[q] = f2bf(Wn[(size_t)(kk * 32 + lk + q) * CG + ct * 16 + lr]);
                d = MFMA(*(const short8*)u, bnod[kk], d, 0, 0, 0);
            }
            #pragma unroll
            for (int i = 0; i < 4; ++i)
                hT[ct * 16 + ks * 4 + i][i0 + lr] = f2bf(d[i] + bn[ct * 16 + ks * 4 + i]);
        }
    }
    __syncthreads();

    // 3 GNN steps: mm1 D[i][j]=adjn·h (halves of j) ; mm2 accumulates over j
    for (int s = 0; s < 3; ++s) {
        f32x4 acc8[8];
        #pragma unroll
        for (int ct = 0; ct < 8; ++ct) acc8[ct] = (f32x4){0.f, 0.f, 0.f, 0.f};
        #pragma unroll
        for (int hf = 0; hf < 2; ++hf) {
            // mm1 half: m[i][jloc] (wave-private rows)
            #pragma unroll
            for (int jt = 0; jt < 4; ++jt) {
                int jg = hf * 64 + jt * 16;
                f32x4 d = {0.f, 0.f, 0.f, 0.f};
                #pragma unroll
                for (int kk = 0; kk < 4; ++kk) {
                    short8 bf = *(const short8*)(&hT[jg + lr][kk * 32 + lk]);
                    d = MFMA(af[kk], bf, d, 0, 0, 0);
                }
                #pragma unroll
                for (int i = 0; i < 4; ++i)
                    mbuf[i0 + ks * 4 + i][jt * 16 + lr] = f2bf(d[i]);
            }
            // mm2 half (register accumulate; K=j-half)
            short8 bm[2];
            #pragma unroll
            for (int kk = 0; kk < 2; ++kk)
                bm[kk] = *(const short8*)(&mbuf[i0 + lr][kk * 32 + lk]);
            #pragma unroll
            for (int ct = 0; ct < 8; ++ct) {
                #pragma unroll
                for (int kk = 0; kk < 2; ++kk) {
                    unsigned short u[8];
                    #pragma unroll
                    for (int q = 0; q < 8; ++q)
                        u[q] = f2bf(Wg[(size_t)(hf * 64 + kk * 32 + lk + q) * CG + ct * 16 + lr]);
                    if (s < 2)   // variant-A: D[c][i], A=WgT-frag, B=m
                        acc8[ct] = MFMA(*(const short8*)u, bm[kk], acc8[ct], 0, 0, 0);
                    else         // variant-B: D[i][c], A=m, B=WgT-frag
                        acc8[ct] = MFMA(bm[kk], *(const short8*)u, acc8[ct], 0, 0, 0);
                }
            }
        }
        __syncthreads();             // all hT reads (both halves) complete
        if (s < 2) {
            #pragma unroll
            for (int ct = 0; ct < 8; ++ct)
                #pragma unroll
                for (int i = 0; i < 4; ++i)
                    hT[ct * 16 + ks * 4 + i][i0 + lr] =
                        f2bf(fmaxf(acc8[ct][i] + sbg[ct * 16 + ks * 4 + i], 0.f));
        } else {
            // node-major write: hT reinterpreted as [n][c]
            #pragma unroll
            for (int ct = 0; ct < 8; ++ct)
                #pragma unroll
                for (int i = 0; i < 4; ++i)
                    hT[i0 + ks * 4 + i][ct * 16 + lr] =
                        f2bf(tanhf(acc8[ct][i] + sbg[ct * 16 + lr]));
        }
        __syncthreads();
    }

    // hW1T[jj][n] = W1topT @ tanh-h  + b1c   (B = hT node-major rows)
    {
        short8 bh[4];
        #pragma unroll
        for (int kk = 0; kk < 4; ++kk)
            bh[kk] = *(const short8*)(&hT[i0 + lr][kk * 32 + lk]);
        #pragma unroll
        for (int jjt = 0; jjt < 12; ++jjt) {
            f32x4 d = {0.f, 0.f, 0.f, 0.f};
            #pragma unroll
            for (int kk = 0; kk < 4; ++kk) {
                unsigned short u[8];
                #pragma unroll
                for (int q = 0; q < 8; ++q)
                    u[q] = f2bf(W1[(size_t)(kk * 32 + lk + q) * HID + jjt * 16 + lr]);
                d = MFMA(*(const short8*)u, bh[kk], d, 0, 0, 0);
            }
            #pragma unroll
            for (int i = 0; i < 4; ++i) {
                int jj = jjt * 16 + ks * 4 + i;
                hW1T[(size_t)b * HID * NN + jj * NN + i0 + lr] = d[i] + b1cL[jj];
            }
        }
    }
}

// ---------------------------------------------------------------------------
// K_GEMM, grid 256 x 512 (1 block/CU, 2 waves/SIMD):
//  block (b, lc): 16 prot rows, all 192 j. Stage-convert A f32->bf16 in LDS
//  (prot read exactly once chip-wide). Wave (w2,wj): K-half w2, 48 j-cols.
//  Partial rW summed via LDS; epilogue vs LDS-staged bf16 hW1T over n-half.
// ---------------------------------------------------------------------------
__global__ __launch_bounds__(512, 1) void k_gemm(
    const float* __restrict__ prot, const unsigned short* __restrict__ WcT,
    const float* __restrict__ hW1T, const float* __restrict__ vbuf,
    float* __restrict__ acc, const float* __restrict__ cconst,
    unsigned* __restrict__ ctr, float* __restrict__ out)
{
    __shared__ char ubuf[57600];
    unsigned short* aT = (unsigned short*)ubuf;        // [16][1032] bf16 (33024B)
    float* pbuf = (float*)(ubuf + 33024);              // [2][16][192] f32 (24576B)
    unsigned short* h1 = (unsigned short*)ubuf;        // [192][136] bf16 (52224B, reuse)
    __shared__ float sred[8];
    __shared__ int lastf;
    int t = threadIdx.x, blk = blockIdx.x;
    int b = blk >> 5, lc = blk & 31;
    int w = t >> 6, l = t & 63, lr = l & 15, ks = l >> 4, lk = ks * 8;
    int w2 = w >> 2, wj = w & 3;

    // stage A: 16 rows x 1024, f32 -> bf16
    {
        int row = t >> 5, seg = t & 31;
        const float* pr = prot + ((size_t)(b * LL + lc * 16 + row)) * RD + seg * 32;
        unsigned short* dst = aT + row * 1032 + seg * 32;
        #pragma unroll
        for (int c8 = 0; c8 < 4; ++c8) {
            float4 p0 = *(const float4*)(pr + c8 * 8);
            float4 p1 = *(const float4*)(pr + c8 * 8 + 4);
            unsigned short u[8];
            u[0]=f2bf(p0.x); u[1]=f2bf(p0.y); u[2]=f2bf(p0.z); u[3]=f2bf(p0.w);
            u[4]=f2bf(p1.x); u[5]=f2bf(p1.y); u[6]=f2bf(p1.z); u[7]=f2bf(p1.w);
            *(short8*)(dst + c8 * 8) = *(const short8*)u;
        }
    }
    __syncthreads();

    // GEMM: K-half per w2
    f32x4 a0 = {0.f,0.f,0.f,0.f}, a1 = a0, a2 = a0;
    {
        const unsigned short* ap = aT + lr * 1032 + w2 * 512 + lk;
        const unsigned short* bp = WcT + (size_t)(wj * 48 + lr) * RD + w2 * 512 + lk;
        #pragma unroll 4
        for (int k0 = 0; k0 < 512; k0 += 32) {
            short8 av = *(const short8*)(ap + k0);
            short8 b0 = *(const short8*)(bp + k0);
            short8 b1 = *(const short8*)(bp + 16 * RD + k0);
            short8 b2 = *(const short8*)(bp + 32 * RD + k0);
            a0 = MFMA(av, b0, a0, 0, 0, 0);
            a1 = MFMA(av, b1, a1, 0, 0, 0);
            a2 = MFMA(av, b2, a2, 0, 0, 0);
        }
    }
    // partial write + combine
    #pragma unroll
    for (int i = 0; i < 4; ++i) {
        int r = ks * 4 + i;
        pbuf[(w2 * 16 + r) * 192 + wj * 48 + lr]      = a0[i];
        pbuf[(w2 * 16 + r) * 192 + wj * 48 + 16 + lr] = a1[i];
        pbuf[(w2 * 16 + r) * 192 + wj * 48 + 32 + lr] = a2[i];
    }
    __syncthreads();
    float rw0[4], rw1[4], rw2[4];
    #pragma unroll
    for (int i = 0; i < 4; ++i) {
        int r = ks * 4 + i;
        rw0[i] = pbuf[r * 192 + wj*48 + lr]      + pbuf[(16 + r) * 192 + wj*48 + lr];
        rw1[i] = pbuf[r * 192 + wj*48 + 16 + lr] + pbuf[(16 + r) * 192 + wj*48 + 16 + lr];
        rw2[i] = pbuf[r * 192 + wj*48 + 32 + lr] + pbuf[(16 + r) * 192 + wj*48 + 32 + lr];
    }
    __syncthreads();

    // restage hW1T[b] -> bf16 LDS [192][136]
    for (int e = t; e < HID * NN; e += 512) {
        int row = e >> 7, n = e & 127;
        h1[row * 136 + n] = f2bf(hW1T[(size_t)b * HID * NN + e]);
    }
    __syncthreads();

    // epilogue over n-half w2
    float v0 = vbuf[wj * 48 + lr];
    float v1 = vbuf[wj * 48 + 16 + lr];
    float v2 = vbuf[wj * 48 + 32 + lr];
    const unsigned short* h0p = h1 + (wj * 48 + lr) * 136 + w2 * 64;
    const unsigned short* h1p = h0p + 16 * 136;
    const unsigned short* h2p = h0p + 32 * 136;
    float s = 0.f;
    #pragma unroll 2
    for (int n0 = 0; n0 < 64; n0 += 4) {
        unsigned short e0[4], e1[4], e2[4];
        *(uint2*)e0 = *(const uint2*)(h0p + n0);
        *(uint2*)e1 = *(const uint2*)(h1p + n0);
        *(uint2*)e2 = *(const uint2*)(h2p + n0);
        #pragma unroll
        for (int q = 0; q < 4; ++q) {
            float hh0 = bf2f(e0[q]), hh1 = bf2f(e1[q]), hh2 = bf2f(e2[q]);
            #pragma unroll
            for (int i = 0; i < 4; ++i) {
                s = fmaf(v0, fmaxf(rw0[i] + hh0, 0.f), s);
                s = fmaf(v1, fmaxf(rw1[i] + hh1, 0.f), s);
                s = fmaf(v2, fmaxf(rw2[i] + hh2, 0.f), s);
            }
        }
    }
    for (int off = 32; off; off >>= 1) s += __shfl_down(s, off);
    if (l == 0) sred[w] = s;
    __syncthreads();
    if (t == 0) {
        float tot = ((sred[0] + sred[1]) + (sred[2] + sred[3]))
                  + ((sred[4] + sred[5]) + (sred[6] + sred[7]));
        atomicAdd(&acc[b], tot);
        __threadfence();
        unsigned old = atomicAdd(ctr, 1u);
        lastf = (old == gridDim.x - 1) ? 1 : 0;
    }
    __syncthreads();
    if (lastf && t < BB)
        out[t] = atomicAdd(&acc[t], 0.0f) + cconst[0];
}

extern "C" void kernel_launch(void* const* d_in, const int* in_sizes, int n_in,
                              void* d_out, int out_size, void* d_ws, size_t ws_size,
                              hipStream_t stream)
{
    const float* adj   = (const float*)d_in[0];
    const float* nodes = (const float*)d_in[1];
    const float* prot  = (const float*)d_in[2];
    const float* Wn    = (const float*)d_in[3];
    const float* bn    = (const float*)d_in[4];
    const float* Wg    = (const float*)d_in[5];
    const float* bg    = (const float*)d_in[6];
    const float* Wr    = (const float*)d_in[7];
    const float* br    = (const float*)d_in[8];
    // d_in[9]=Wa, d_in[10]=ba: unused (softmax over size-1 axis == 1)
    const float* W1    = (const float*)d_in[11];
    const float* b1    = (const float*)d_in[12];
    const float* W2    = (const float*)d_in[13];
    const float* b2    = (const float*)d_in[14];
    const float* Wo    = (const float*)d_in[15];
    const float* bo    = (const float*)d_in[16];

    float* ws     = (float*)d_ws;
    float* hW1T   = ws;                        // [8][192][128] f32 = 196608
    float* vbuf   = ws + 196608;               // [192]
    float* cconst = ws + 196800;               // [1]
    float* accb   = ws + 196804;               // [8]
    unsigned* ctr = (unsigned*)(ws + 196812);  // [1]
    unsigned short* WcT = (unsigned short*)(ws + 196816); // [192][1024] bf16
    float* out    = (float*)d_out;

    hipLaunchKernelGGL(k_prep, dim3(73), dim3(512), 0, stream,
                       adj, nodes, Wn, bn, Wr, br, W1, b1, Wg, bg,
                       W2, b2, Wo, bo, WcT, hW1T, vbuf, cconst, accb, ctr);
    hipLaunchKernelGGL(k_gemm, dim3(256), dim3(512), 0, stream,
                       prot, WcT, hW1T, vbuf, accb, cconst, ctr, out);
}

// Round 12
// 61.132 us; speedup vs baseline: 2.1414x; 1.1750x over previous
//
#include <hip/hip_runtime.h>

#define BB 8
#define NN 128
#define ND 64
#define LL 512
#define RD 1024
#define CG 128
#define HID 192

typedef __attribute__((ext_vector_type(8))) short short8;
typedef __attribute__((ext_vector_type(4))) float f32x4;

__device__ __forceinline__ unsigned short f2bf(float x) {
    unsigned u = __builtin_bit_cast(unsigned, x);
    u += 0x7fffu + ((u >> 16) & 1u);          // RNE
    return (unsigned short)(u >> 16);
}
__device__ __forceinline__ float bf2f(unsigned short h) {
    unsigned u = ((unsigned)h) << 16;
    return __builtin_bit_cast(float, u);
}
#define MFMA __builtin_amdgcn_mfma_f32_16x16x32_bf16

// ---------------------------------------------------------------------------
// K_PREP, grid 73 x 512 (139KB LDS, 1 block/CU; 73 blocks all co-resident):
//  blk 0..63 : WcT[c][k] = bf16((Wr@W1b)[k][c]), 16 k-rows/block (VALU)
//  blk 64    : vbuf = W2@Wo ; cconst ; acc=0 ; ctr=0
//  blk 65..72: per-batch GNN, all-MFMA. Weight fragments staged ONCE into
//              LDS (coalesced) -> all MFMA operands are ds_read_b128.
//              Norms folded into adjn (regs). Writes hW1T[b][192][128] f32.
// ---------------------------------------------------------------------------
__global__ __launch_bounds__(512, 1) void k_prep(
    const float* __restrict__ adj, const float* __restrict__ nodes,
    const float* __restrict__ Wn, const float* __restrict__ bn,
    const float* __restrict__ Wr, const float* __restrict__ br,
    const float* __restrict__ W1, const float* __restrict__ b1,
    const float* __restrict__ Wg, const float* __restrict__ bg,
    const float* __restrict__ W2, const float* __restrict__ b2,
    const float* __restrict__ Wo, const float* __restrict__ bo,
    unsigned short* __restrict__ WcT, float* __restrict__ hW1T,
    float* __restrict__ vbuf, float* __restrict__ cconst,
    float* __restrict__ acc, unsigned* __restrict__ ctr)
{
    __shared__ unsigned short hT[NN][136];    // 34.8KB h (feature-major, later node-major)
    __shared__ unsigned short mbuf[NN][72];   // 18.4KB m half / WnT / deg scratch
    __shared__ unsigned short WgT[NN][136];   // 34.8KB WgT[c][j]
    __shared__ unsigned short W1T[HID][136];  // 52.2KB W1T[jj][k]
    __shared__ float snorm[NN];
    __shared__ float b1cL[HID];
    __shared__ float sbg[NN];
    int t = threadIdx.x, blk = blockIdx.x;
    const float* W1b = W1 + CG * HID;

    if (blk < 64) {
        int r0 = blk * 16;
        float* sW = (float*)&hT[0][0];       // 16x128 f32 scratch
        for (int e = t; e < 16 * CG; e += 512) sW[e] = Wr[(size_t)r0 * CG + e];
        __syncthreads();
        for (int o = t; o < 16 * HID; o += 512) {
            int r = o / HID, c = o % HID;
            float s = 0.f;
            #pragma unroll 8
            for (int m = 0; m < CG; ++m)
                s = fmaf(sW[r * CG + m], W1b[(size_t)m * HID + c], s);
            WcT[(size_t)c * RD + r0 + r] = f2bf(s);
        }
        return;
    }
    if (blk == 64) {
        if (t < HID) {
            float s = 0.f;
            #pragma unroll 8
            for (int k = 0; k < CG; ++k) s = fmaf(W2[t * CG + k], Wo[k], s);
            vbuf[t] = s;
        }
        if (t == 511) {
            float s = 0.f;
            for (int k = 0; k < CG; ++k) s = fmaf(b2[k], Wo[k], s);
            cconst[0] = (float)(NN * LL) * s + bo[0];
        }
        if (t == 510) *ctr = 0u;
        if (t < BB) acc[t] = 0.f;
        return;
    }

    // ---------------- GNN block, batch b ----------------
    int b = blk - 65;
    int w = t >> 6, l = t & 63, lr = l & 15, ks = l >> 4, lk = ks * 8;
    int i0 = w * 16;

    // P0: degrees (scratch in mbuf)
    {
        float* dscr = (float*)&mbuf[0][0];   // [128][4] f32
        int row = t >> 2, q4 = t & 3;
        const float* ar = adj + ((size_t)b * NN + row) * NN + q4 * 32;
        float d = 0.f;
        #pragma unroll
        for (int c4 = 0; c4 < 8; ++c4) {
            float4 p = *(const float4*)(ar + c4 * 4);
            d += (p.x + p.y) + (p.z + p.w);
        }
        dscr[row * 4 + q4] = d;
        __syncthreads();
        if (t < NN) {
            snorm[t] = rsqrtf(fmaxf(dscr[t*4] + dscr[t*4+1] + dscr[t*4+2] + dscr[t*4+3], 1.f));
        } else if (t < 320) {
            int j = t - 128;
            float s = b1[j];
            #pragma unroll 8
            for (int m = 0; m < CG; ++m)
                s = fmaf(br[m], W1b[(size_t)m * HID + j], s);
            b1cL[j] = s;
        } else if (t < 448) {
            sbg[t - 320] = bg[t - 320];
        }
        __syncthreads();
    }

    // P1: stage WnT (in mbuf), WgT, W1T into LDS — all reads coalesced,
    //     all writes 2-way-conflict-free (stride 272B / 144B).
    unsigned short* WnT = &mbuf[0][0];       // [128][72]
    #pragma unroll
    for (int q = 0; q < 16; ++q) {           // WnT[c][k] = Wn[k][c], 8192 elems
        int e = t + 512 * q;
        int c = e & 127, k = e >> 7;
        WnT[c * 72 + k] = f2bf(Wn[(size_t)k * CG + c]);
    }
    #pragma unroll
    for (int q = 0; q < 32; ++q) {           // WgT[c][j] = Wg[j][c], 16384 elems
        int e = t + 512 * q;
        int c = e & 127, j = e >> 7;
        WgT[c][j] = f2bf(Wg[(size_t)j * CG + c]);
    }
    #pragma unroll
    for (int q = 0; q < 32; ++q) {           // W1T[jj][k] = W1[k][jj], jj<128
        int e = t + 512 * q;
        int jj = e & 127, k = e >> 7;
        W1T[jj][k] = f2bf(W1[(size_t)k * HID + jj]);
    }
    #pragma unroll
    for (int q = 0; q < 16; ++q) {           // W1T[jj][k], jj 128..191
        int e = t + 512 * q;
        int jj = 128 + (e & 63), k = e >> 6;
        W1T[jj][k] = f2bf(W1[(size_t)k * HID + jj]);
    }

    // adjn fragments in regs: adjn[i][k] = adj[i][k]*norm[i]*norm[k] (bf16)
    short8 af[4];
    {
        float ni = snorm[i0 + lr];
        const float* ar = adj + ((size_t)b * NN + i0 + lr) * NN;
        #pragma unroll
        for (int kk = 0; kk < 4; ++kk) {
            int kb = kk * 32 + lk;
            float4 p0 = *(const float4*)(ar + kb);
            float4 p1 = *(const float4*)(ar + kb + 4);
            unsigned short u[8];
            u[0] = f2bf(p0.x * ni * snorm[kb+0]); u[1] = f2bf(p0.y * ni * snorm[kb+1]);
            u[2] = f2bf(p0.z * ni * snorm[kb+2]); u[3] = f2bf(p0.w * ni * snorm[kb+3]);
            u[4] = f2bf(p1.x * ni * snorm[kb+4]); u[5] = f2bf(p1.y * ni * snorm[kb+5]);
            u[6] = f2bf(p1.z * ni * snorm[kb+6]); u[7] = f2bf(p1.w * ni * snorm[kb+7]);
            af[kk] = *(const short8*)u;
        }
    }
    // nodes fragments (coalesced f32 + cvt)
    short8 bnod[2];
    #pragma unroll
    for (int kk = 0; kk < 2; ++kk) {
        const float* np = nodes + ((size_t)b * NN + i0 + lr) * ND + kk * 32 + lk;
        float4 q0 = *(const float4*)np;
        float4 q1 = *(const float4*)(np + 4);
        unsigned short u[8];
        u[0]=f2bf(q0.x); u[1]=f2bf(q0.y); u[2]=f2bf(q0.z); u[3]=f2bf(q0.w);
        u[4]=f2bf(q1.x); u[5]=f2bf(q1.y); u[6]=f2bf(q1.z); u[7]=f2bf(q1.w);
        bnod[kk] = *(const short8*)u;
    }
    __syncthreads();

    // P2: h0 = nodes@Wn + bn -> hT[c][n] feature-major (Wn frags from LDS)
    #pragma unroll
    for (int ct = 0; ct < 8; ++ct) {
        f32x4 d = {0.f, 0.f, 0.f, 0.f};
        #pragma unroll
        for (int kk = 0; kk < 2; ++kk) {
            short8 afw = *(const short8*)(WnT + (ct * 16 + lr) * 72 + kk * 32 + lk);
            d = MFMA(afw, bnod[kk], d, 0, 0, 0);
        }
        #pragma unroll
        for (int i = 0; i < 4; ++i)
            hT[ct * 16 + ks * 4 + i][i0 + lr] = f2bf(d[i] + bn[ct * 16 + ks * 4 + i]);
    }
    __syncthreads();    // also: WnT (mbuf) free after this barrier

    // P3: 3 GNN steps (all operand reads = ds_read_b128)
    for (int s = 0; s < 3; ++s) {
        f32x4 acc8[8];
        #pragma unroll
        for (int ct = 0; ct < 8; ++ct) acc8[ct] = (f32x4){0.f, 0.f, 0.f, 0.f};
        #pragma unroll
        for (int hf = 0; hf < 2; ++hf) {
            #pragma unroll
            for (int jt = 0; jt < 4; ++jt) {
                int jg = hf * 64 + jt * 16;
                f32x4 d = {0.f, 0.f, 0.f, 0.f};
                #pragma unroll
                for (int kk = 0; kk < 4; ++kk) {
                    short8 bf = *(const short8*)(&hT[jg + lr][kk * 32 + lk]);
                    d = MFMA(af[kk], bf, d, 0, 0, 0);
                }
                #pragma unroll
                for (int i = 0; i < 4; ++i)
                    mbuf[i0 + ks * 4 + i][jt * 16 + lr] = f2bf(d[i]);
            }
            short8 bm[2];
            #pragma unroll
            for (int kk = 0; kk < 2; ++kk)
                bm[kk] = *(const short8*)(&mbuf[i0 + lr][kk * 32 + lk]);
            #pragma unroll
            for (int ct = 0; ct < 8; ++ct) {
                #pragma unroll
                for (int kk = 0; kk < 2; ++kk) {
                    short8 wf = *(const short8*)(&WgT[ct * 16 + lr][hf * 64 + kk * 32 + lk]);
                    if (s < 2)
                        acc8[ct] = MFMA(wf, bm[kk], acc8[ct], 0, 0, 0);
                    else
                        acc8[ct] = MFMA(bm[kk], wf, acc8[ct], 0, 0, 0);
                }
            }
        }
        __syncthreads();
        if (s < 2) {
            #pragma unroll
            for (int ct = 0; ct < 8; ++ct)
                #pragma unroll
                for (int i = 0; i < 4; ++i)
                    hT[ct * 16 + ks * 4 + i][i0 + lr] =
                        f2bf(fmaxf(acc8[ct][i] + sbg[ct * 16 + ks * 4 + i], 0.f));
        } else {
            #pragma unroll
            for (int ct = 0; ct < 8; ++ct)
                #pragma unroll
                for (int i = 0; i < 4; ++i)
                    hT[i0 + ks * 4 + i][ct * 16 + lr] =
                        f2bf(tanhf(acc8[ct][i] + sbg[ct * 16 + lr]));
        }
        __syncthreads();
    }

    // P4: hW1T[jj][n] = W1topT @ tanh-h + b1c  (W1 frags from LDS)
    {
        short8 bh[4];
        #pragma unroll
        for (int kk = 0; kk < 4; ++kk)
            bh[kk] = *(const short8*)(&hT[i0 + lr][kk * 32 + lk]);
        #pragma unroll
        for (int jjt = 0; jjt < 12; ++jjt) {
            f32x4 d = {0.f, 0.f, 0.f, 0.f};
            #pragma unroll
            for (int kk = 0; kk < 4; ++kk) {
                short8 wf = *(const short8*)(&W1T[jjt * 16 + lr][kk * 32 + lk]);
                d = MFMA(wf, bh[kk], d, 0, 0, 0);
            }
            #pragma unroll
            for (int i = 0; i < 4; ++i) {
                int jj = jjt * 16 + ks * 4 + i;
                hW1T[(size_t)b * HID * NN + jj * NN + i0 + lr] = d[i] + b1cL[jj];
            }
        }
    }
}

// ---------------------------------------------------------------------------
// K_GEMM, grid 256 x 512 (1 block/CU, 2 waves/SIMD)  [R11-verified]:
//  block (b, lc): 16 prot rows, all 192 j. Stage-convert A f32->bf16 in LDS.
//  Wave (w2,wj): K-half w2, 48 j-cols. LDS partial combine; epilogue vs
//  LDS-staged bf16 hW1T over n-half.
// ---------------------------------------------------------------------------
__global__ __launch_bounds__(512, 1) void k_gemm(
    const float* __restrict__ prot, const unsigned short* __restrict__ WcT,
    const float* __restrict__ hW1T, const float* __restrict__ vbuf,
    float* __restrict__ acc, const float* __restrict__ cconst,
    unsigned* __restrict__ ctr, float* __restrict__ out)
{
    __shared__ char ubuf[57600];
    unsigned short* aT = (unsigned short*)ubuf;        // [16][1032] bf16
    float* pbuf = (float*)(ubuf + 33024);              // [2][16][192] f32
    unsigned short* h1 = (unsigned short*)ubuf;        // [192][136] bf16 (reuse)
    __shared__ float sred[8];
    __shared__ int lastf;
    int t = threadIdx.x, blk = blockIdx.x;
    int b = blk >> 5, lc = blk & 31;
    int w = t >> 6, l = t & 63, lr = l & 15, ks = l >> 4, lk = ks * 8;
    int w2 = w >> 2, wj = w & 3;

    {
        int row = t >> 5, seg = t & 31;
        const float* pr = prot + ((size_t)(b * LL + lc * 16 + row)) * RD + seg * 32;
        unsigned short* dst = aT + row * 1032 + seg * 32;
        #pragma unroll
        for (int c8 = 0; c8 < 4; ++c8) {
            float4 p0 = *(const float4*)(pr + c8 * 8);
            float4 p1 = *(const float4*)(pr + c8 * 8 + 4);
            unsigned short u[8];
            u[0]=f2bf(p0.x); u[1]=f2bf(p0.y); u[2]=f2bf(p0.z); u[3]=f2bf(p0.w);
            u[4]=f2bf(p1.x); u[5]=f2bf(p1.y); u[6]=f2bf(p1.z); u[7]=f2bf(p1.w);
            *(short8*)(dst + c8 * 8) = *(const short8*)u;
        }
    }
    __syncthreads();

    f32x4 a0 = {0.f,0.f,0.f,0.f}, a1 = a0, a2 = a0;
    {
        const unsigned short* ap = aT + lr * 1032 + w2 * 512 + lk;
        const unsigned short* bp = WcT + (size_t)(wj * 48 + lr) * RD + w2 * 512 + lk;
        #pragma unroll 4
        for (int k0 = 0; k0 < 512; k0 += 32) {
            short8 av = *(const short8*)(ap + k0);
            short8 b0 = *(const short8*)(bp + k0);
            short8 b1 = *(const short8*)(bp + 16 * RD + k0);
            short8 b2 = *(const short8*)(bp + 32 * RD + k0);
            a0 = MFMA(av, b0, a0, 0, 0, 0);
            a1 = MFMA(av, b1, a1, 0, 0, 0);
            a2 = MFMA(av, b2, a2, 0, 0, 0);
        }
    }
    #pragma unroll
    for (int i = 0; i < 4; ++i) {
        int r = ks * 4 + i;
        pbuf[(w2 * 16 + r) * 192 + wj * 48 + lr]      = a0[i];
        pbuf[(w2 * 16 + r) * 192 + wj * 48 + 16 + lr] = a1[i];
        pbuf[(w2 * 16 + r) * 192 + wj * 48 + 32 + lr] = a2[i];
    }
    __syncthreads();
    float rw0[4], rw1[4], rw2[4];
    #pragma unroll
    for (int i = 0; i < 4; ++i) {
        int r = ks * 4 + i;
        rw0[i] = pbuf[r * 192 + wj*48 + lr]      + pbuf[(16 + r) * 192 + wj*48 + lr];
        rw1[i] = pbuf[r * 192 + wj*48 + 16 + lr] + pbuf[(16 + r) * 192 + wj*48 + 16 + lr];
        rw2[i] = pbuf[r * 192 + wj*48 + 32 + lr] + pbuf[(16 + r) * 192 + wj*48 + 32 + lr];
    }
    __syncthreads();

    for (int e = t; e < HID * NN; e += 512) {
        int row = e >> 7, n = e & 127;
        h1[row * 136 + n] = f2bf(hW1T[(size_t)b * HID * NN + e]);
    }
    __syncthreads();

    float v0 = vbuf[wj * 48 + lr];
    float v1 = vbuf[wj * 48 + 16 + lr];
    float v2 = vbuf[wj * 48 + 32 + lr];
    const unsigned short* h0p = h1 + (wj * 48 + lr) * 136 + w2 * 64;
    const unsigned short* h1p = h0p + 16 * 136;
    const unsigned short* h2p = h0p + 32 * 136;
    float s = 0.f;
    #pragma unroll 2
    for (int n0 = 0; n0 < 64; n0 += 4) {
        unsigned short e0[4], e1[4], e2[4];
        *(uint2*)e0 = *(const uint2*)(h0p + n0);
        *(uint2*)e1 = *(const uint2*)(h1p + n0);
        *(uint2*)e2 = *(const uint2*)(h2p + n0);
        #pragma unroll
        for (int q = 0; q < 4; ++q) {
            float hh0 = bf2f(e0[q]), hh1 = bf2f(e1[q]), hh2 = bf2f(e2[q]);
            #pragma unroll
            for (int i = 0; i < 4; ++i) {
                s = fmaf(v0, fmaxf(rw0[i] + hh0, 0.f), s);
                s = fmaf(v1, fmaxf(rw1[i] + hh1, 0.f), s);
                s = fmaf(v2, fmaxf(rw2[i] + hh2, 0.f), s);
            }
        }
    }
    for (int off = 32; off; off >>= 1) s += __shfl_down(s, off);
    if (l == 0) sred[w] = s;
    __syncthreads();
    if (t == 0) {
        float tot = ((sred[0] + sred[1]) + (sred[2] + sred[3]))
                  + ((sred[4] + sred[5]) + (sred[6] + sred[7]));
        atomicAdd(&acc[b], tot);
        __threadfence();
        unsigned old = atomicAdd(ctr, 1u);
        lastf = (old == gridDim.x - 1) ? 1 : 0;
    }
    __syncthreads();
    if (lastf && t < BB)
        out[t] = atomicAdd(&acc[t], 0.0f) + cconst[0];
}

extern "C" void kernel_launch(void* const* d_in, const int* in_sizes, int n_in,
                              void* d_out, int out_size, void* d_ws, size_t ws_size,
                              hipStream_t stream)
{
    const float* adj   = (const float*)d_in[0];
    const float* nodes = (const float*)d_in[1];
    const float* prot  = (const float*)d_in[2];
    const float* Wn    = (const float*)d_in[3];
    const float* bn    = (const float*)d_in[4];
    const float* Wg    = (const float*)d_in[5];
    const float* bg    = (const float*)d_in[6];
    const float* Wr    = (const float*)d_in[7];
    const float* br    = (const float*)d_in[8];
    // d_in[9]=Wa, d_in[10]=ba: unused (softmax over size-1 axis == 1)
    const float* W1    = (const float*)d_in[11];
    const float* b1    = (const float*)d_in[12];
    const float* W2    = (const float*)d_in[13];
    const float* b2    = (const float*)d_in[14];
    const float* Wo    = (const float*)d_in[15];
    const float* bo    = (const float*)d_in[16];

    float* ws     = (float*)d_ws;
    float* hW1T   = ws;                        // [8][192][128] f32 = 196608
    float* vbuf   = ws + 196608;               // [192]
    float* cconst = ws + 196800;               // [1]
    float* accb   = ws + 196804;               // [8]
    unsigned* ctr = (unsigned*)(ws + 196812);  // [1]
    unsigned short* WcT = (unsigned short*)(ws + 196816); // [192][1024] bf16
    float* out    = (float*)d_out;

    hipLaunchKernelGGL(k_prep, dim3(73), dim3(512), 0, stream,
                       adj, nodes, Wn, bn, Wr, br, W1, b1, Wg, bg,
                       W2, b2, Wo, bo, WcT, hW1T, vbuf, cconst, accb, ctr);
    hipLaunchKernelGGL(k_gemm, dim3(256), dim3(512), 0, stream,
                       prot, WcT, hW1T, vbuf, accb, cconst, ctr, out);
}

// Round 13
// 56.371 us; speedup vs baseline: 2.3223x; 1.0845x over previous
//
#include <hip/hip_runtime.h>

#define BB 8
#define NN 128
#define ND 64
#define LL 512
#define RD 1024
#define CG 128
#define HID 192

typedef __attribute__((ext_vector_type(8))) short short8;
typedef __attribute__((ext_vector_type(4))) float f32x4;

__device__ __forceinline__ unsigned short f2bf(float x) {
    unsigned u = __builtin_bit_cast(unsigned, x);
    u += 0x7fffu + ((u >> 16) & 1u);          // RNE
    return (unsigned short)(u >> 16);
}
__device__ __forceinline__ float bf2f(unsigned short h) {
    unsigned u = ((unsigned)h) << 16;
    return __builtin_bit_cast(float, u);
}
#define MFMA __builtin_amdgcn_mfma_f32_16x16x32_bf16

// ---------------------------------------------------------------------------
// K_PREP, grid 25 x 512 (139KB LDS, 1 block/CU; all co-resident):
//  blk 0..15 : WcT[c][k] = bf16((Wr@W1b)[k][c]) via MFMA, 64 k-rows/block.
//              W1bT staged in LDS (reuses W1T array).
//  blk 16    : vbuf = W2@Wo ; out[b] = cconst (base for k_gemm atomics)
//  blk 17..24: per-batch GNN, all-MFMA, weights staged once in LDS,
//              norms folded into adjn (regs). Writes hW1T[b][192][128] f32.
// ---------------------------------------------------------------------------
__global__ __launch_bounds__(512, 1) void k_prep(
    const float* __restrict__ adj, const float* __restrict__ nodes,
    const float* __restrict__ Wn, const float* __restrict__ bn,
    const float* __restrict__ Wr, const float* __restrict__ br,
    const float* __restrict__ W1, const float* __restrict__ b1,
    const float* __restrict__ Wg, const float* __restrict__ bg,
    const float* __restrict__ W2, const float* __restrict__ b2,
    const float* __restrict__ Wo, const float* __restrict__ bo,
    unsigned short* __restrict__ WcT, float* __restrict__ hW1T,
    float* __restrict__ vbuf, float* __restrict__ out)
{
    __shared__ unsigned short hT[NN][136];    // 34.8KB h (feature-major / node-major)
    __shared__ unsigned short mbuf[NN][72];   // 18.4KB m half / WnT / deg scratch
    __shared__ unsigned short WgT[NN][136];   // 34.8KB WgT[c][j]
    __shared__ unsigned short W1T[HID][136];  // 52.2KB W1T[jj][k]  (W1bT in WcT blocks)
    __shared__ float snorm[NN];
    __shared__ float b1cL[HID];
    __shared__ float sbg[NN];
    int t = threadIdx.x, blk = blockIdx.x;
    int w = t >> 6, l = t & 63, lr = l & 15, ks = l >> 4, lk = ks * 8;
    const float* W1b = W1 + CG * HID;

    if (blk < 16) {
        // ---- WcT via MFMA: 64 k-rows (r0..r0+63), all 192 c ----
        int r0 = blk * 64;
        // stage W1bT[c][m] into W1T array (coalesced global reads)
        #pragma unroll
        for (int q = 0; q < 48; ++q) {
            int e = t + 512 * q;              // 0..24575
            int m = e / HID, c = e % HID;
            W1T[c][m] = f2bf(W1[(size_t)(CG + m) * HID + c]);
        }
        // A fragments: wave -> row-tile rt (16 k-rows), j-half jh (6 j-tiles)
        int rt = w & 3, jh = w >> 2;
        short8 awr[4];
        #pragma unroll
        for (int kk = 0; kk < 4; ++kk) {
            const float* wp = Wr + (size_t)(r0 + rt * 16 + lr) * CG + kk * 32 + lk;
            float4 q0 = *(const float4*)wp;
            float4 q1 = *(const float4*)(wp + 4);
            unsigned short u[8];
            u[0]=f2bf(q0.x); u[1]=f2bf(q0.y); u[2]=f2bf(q0.z); u[3]=f2bf(q0.w);
            u[4]=f2bf(q1.x); u[5]=f2bf(q1.y); u[6]=f2bf(q1.z); u[7]=f2bf(q1.w);
            awr[kk] = *(const short8*)u;
        }
        __syncthreads();
        #pragma unroll
        for (int jt6 = 0; jt6 < 6; ++jt6) {
            int jt = jh * 6 + jt6;            // 0..11
            f32x4 d = {0.f, 0.f, 0.f, 0.f};
            #pragma unroll
            for (int kk = 0; kk < 4; ++kk) {
                short8 bf = *(const short8*)(&W1T[jt * 16 + lr][kk * 32 + lk]);
                d = MFMA(awr[kk], bf, d, 0, 0, 0);
            }
            unsigned short u[4];
            #pragma unroll
            for (int i = 0; i < 4; ++i) u[i] = f2bf(d[i]);
            *(uint2*)(WcT + (size_t)(jt * 16 + lr) * RD + r0 + rt * 16 + ks * 4) = *(uint2*)u;
        }
        return;
    }
    if (blk == 16) {
        if (t < HID) {
            float s = 0.f;
            #pragma unroll 8
            for (int k = 0; k < CG; ++k) s = fmaf(W2[t * CG + k], Wo[k], s);
            vbuf[t] = s;
        }
        if (t < BB) {
            float s = 0.f;
            for (int k = 0; k < CG; ++k) s = fmaf(b2[k], Wo[k], s);
            out[t] = (float)(NN * LL) * s + bo[0];   // cconst base
        }
        return;
    }

    // ---------------- GNN block, batch b ----------------
    int b = blk - 17;
    int i0 = w * 16;

    // P0: degrees (scratch in mbuf) ; b1c ; stage bg
    {
        float* dscr = (float*)&mbuf[0][0];   // [128][4] f32
        int row = t >> 2, q4 = t & 3;
        const float* ar = adj + ((size_t)b * NN + row) * NN + q4 * 32;
        float d = 0.f;
        #pragma unroll
        for (int c4 = 0; c4 < 8; ++c4) {
            float4 p = *(const float4*)(ar + c4 * 4);
            d += (p.x + p.y) + (p.z + p.w);
        }
        dscr[row * 4 + q4] = d;
        __syncthreads();
        if (t < NN) {
            snorm[t] = rsqrtf(fmaxf(dscr[t*4] + dscr[t*4+1] + dscr[t*4+2] + dscr[t*4+3], 1.f));
        } else if (t < 320) {
            int j = t - 128;
            float s = b1[j];
            #pragma unroll 8
            for (int m = 0; m < CG; ++m)
                s = fmaf(br[m], W1b[(size_t)m * HID + j], s);
            b1cL[j] = s;
        } else if (t < 448) {
            sbg[t - 320] = bg[t - 320];
        }
        __syncthreads();
    }

    // P1: stage WnT (mbuf), WgT, W1T into LDS (coalesced reads)
    unsigned short* WnT = &mbuf[0][0];       // [128][72]
    #pragma unroll
    for (int q = 0; q < 16; ++q) {
        int e = t + 512 * q;
        int c = e & 127, k = e >> 7;
        WnT[c * 72 + k] = f2bf(Wn[(size_t)k * CG + c]);
    }
    #pragma unroll
    for (int q = 0; q < 32; ++q) {
        int e = t + 512 * q;
        int c = e & 127, j = e >> 7;
        WgT[c][j] = f2bf(Wg[(size_t)j * CG + c]);
    }
    #pragma unroll
    for (int q = 0; q < 32; ++q) {
        int e = t + 512 * q;
        int jj = e & 127, k = e >> 7;
        W1T[jj][k] = f2bf(W1[(size_t)k * HID + jj]);
    }
    #pragma unroll
    for (int q = 0; q < 16; ++q) {
        int e = t + 512 * q;
        int jj = 128 + (e & 63), k = e >> 6;
        W1T[jj][k] = f2bf(W1[(size_t)k * HID + jj]);
    }

    // adjn fragments: adjn[i][k] = adj[i][k]*norm[i]*norm[k] (bf16, regs)
    short8 af[4];
    {
        float ni = snorm[i0 + lr];
        const float* ar = adj + ((size_t)b * NN + i0 + lr) * NN;
        #pragma unroll
        for (int kk = 0; kk < 4; ++kk) {
            int kb = kk * 32 + lk;
            float4 p0 = *(const float4*)(ar + kb);
            float4 p1 = *(const float4*)(ar + kb + 4);
            unsigned short u[8];
            u[0] = f2bf(p0.x * ni * snorm[kb+0]); u[1] = f2bf(p0.y * ni * snorm[kb+1]);
            u[2] = f2bf(p0.z * ni * snorm[kb+2]); u[3] = f2bf(p0.w * ni * snorm[kb+3]);
            u[4] = f2bf(p1.x * ni * snorm[kb+4]); u[5] = f2bf(p1.y * ni * snorm[kb+5]);
            u[6] = f2bf(p1.z * ni * snorm[kb+6]); u[7] = f2bf(p1.w * ni * snorm[kb+7]);
            af[kk] = *(const short8*)u;
        }
    }
    short8 bnod[2];
    #pragma unroll
    for (int kk = 0; kk < 2; ++kk) {
        const float* np = nodes + ((size_t)b * NN + i0 + lr) * ND + kk * 32 + lk;
        float4 q0 = *(const float4*)np;
        float4 q1 = *(const float4*)(np + 4);
        unsigned short u[8];
        u[0]=f2bf(q0.x); u[1]=f2bf(q0.y); u[2]=f2bf(q0.z); u[3]=f2bf(q0.w);
        u[4]=f2bf(q1.x); u[5]=f2bf(q1.y); u[6]=f2bf(q1.z); u[7]=f2bf(q1.w);
        bnod[kk] = *(const short8*)u;
    }
    __syncthreads();

    // P2: h0 = nodes@Wn + bn -> hT[c][n] feature-major
    #pragma unroll
    for (int ct = 0; ct < 8; ++ct) {
        f32x4 d = {0.f, 0.f, 0.f, 0.f};
        #pragma unroll
        for (int kk = 0; kk < 2; ++kk) {
            short8 afw = *(const short8*)(WnT + (ct * 16 + lr) * 72 + kk * 32 + lk);
            d = MFMA(afw, bnod[kk], d, 0, 0, 0);
        }
        #pragma unroll
        for (int i = 0; i < 4; ++i)
            hT[ct * 16 + ks * 4 + i][i0 + lr] = f2bf(d[i] + bn[ct * 16 + ks * 4 + i]);
    }
    __syncthreads();

    // P3: 3 GNN steps (ds_read_b128 operands)
    for (int s = 0; s < 3; ++s) {
        f32x4 acc8[8];
        #pragma unroll
        for (int ct = 0; ct < 8; ++ct) acc8[ct] = (f32x4){0.f, 0.f, 0.f, 0.f};
        #pragma unroll
        for (int hf = 0; hf < 2; ++hf) {
            #pragma unroll
            for (int jt = 0; jt < 4; ++jt) {
                int jg = hf * 64 + jt * 16;
                f32x4 d = {0.f, 0.f, 0.f, 0.f};
                #pragma unroll
                for (int kk = 0; kk < 4; ++kk) {
                    short8 bf = *(const short8*)(&hT[jg + lr][kk * 32 + lk]);
                    d = MFMA(af[kk], bf, d, 0, 0, 0);
                }
                #pragma unroll
                for (int i = 0; i < 4; ++i)
                    mbuf[i0 + ks * 4 + i][jt * 16 + lr] = f2bf(d[i]);
            }
            short8 bm[2];
            #pragma unroll
            for (int kk = 0; kk < 2; ++kk)
                bm[kk] = *(const short8*)(&mbuf[i0 + lr][kk * 32 + lk]);
            #pragma unroll
            for (int ct = 0; ct < 8; ++ct) {
                #pragma unroll
                for (int kk = 0; kk < 2; ++kk) {
                    short8 wf = *(const short8*)(&WgT[ct * 16 + lr][hf * 64 + kk * 32 + lk]);
                    if (s < 2)
                        acc8[ct] = MFMA(wf, bm[kk], acc8[ct], 0, 0, 0);
                    else
                        acc8[ct] = MFMA(bm[kk], wf, acc8[ct], 0, 0, 0);
                }
            }
        }
        __syncthreads();
        if (s < 2) {
            #pragma unroll
            for (int ct = 0; ct < 8; ++ct)
                #pragma unroll
                for (int i = 0; i < 4; ++i)
                    hT[ct * 16 + ks * 4 + i][i0 + lr] =
                        f2bf(fmaxf(acc8[ct][i] + sbg[ct * 16 + ks * 4 + i], 0.f));
        } else {
            #pragma unroll
            for (int ct = 0; ct < 8; ++ct)
                #pragma unroll
                for (int i = 0; i < 4; ++i)
                    hT[i0 + ks * 4 + i][ct * 16 + lr] =
                        f2bf(tanhf(acc8[ct][i] + sbg[ct * 16 + lr]));
        }
        __syncthreads();
    }

    // P4: hW1T[jj][n] = W1topT @ tanh-h + b1c
    {
        short8 bh[4];
        #pragma unroll
        for (int kk = 0; kk < 4; ++kk)
            bh[kk] = *(const short8*)(&hT[i0 + lr][kk * 32 + lk]);
        #pragma unroll
        for (int jjt = 0; jjt < 12; ++jjt) {
            f32x4 d = {0.f, 0.f, 0.f, 0.f};
            #pragma unroll
            for (int kk = 0; kk < 4; ++kk) {
                short8 wf = *(const short8*)(&W1T[jjt * 16 + lr][kk * 32 + lk]);
                d = MFMA(wf, bh[kk], d, 0, 0, 0);
            }
            #pragma unroll
            for (int i = 0; i < 4; ++i) {
                int jj = jjt * 16 + ks * 4 + i;
                hW1T[(size_t)b * HID * NN + jj * NN + i0 + lr] = d[i] + b1cL[jj];
            }
        }
    }
}

// ---------------------------------------------------------------------------
// K_GEMM, grid 256 x 512 (1 block/CU):
//  block (b, lc): 16 prot rows, all 192 j. A f32->bf16 staged in LDS; hW1T
//  restaged bf16 in a SEPARATE buffer before the same barrier (overlapped).
//  Wave (w2,wj): K-half w2, 48 j-cols. LDS partial combine; fused pairsum
//  epilogue; ONE atomicAdd(&out[b]) per block (out pre-set to cconst).
// ---------------------------------------------------------------------------
__global__ __launch_bounds__(512, 1) void k_gemm(
    const float* __restrict__ prot, const unsigned short* __restrict__ WcT,
    const float* __restrict__ hW1T, const float* __restrict__ vbuf,
    float* __restrict__ out)
{
    __shared__ unsigned short aT[16 * 1032];   // 33024B
    __shared__ unsigned short h1[HID * 136];   // 52224B
    __shared__ float pbuf[2 * 16 * 192];       // 24576B
    __shared__ float sred[8];
    int t = threadIdx.x, blk = blockIdx.x;
    int b = blk >> 5, lc = blk & 31;
    int w = t >> 6, l = t & 63, lr = l & 15, ks = l >> 4, lk = ks * 8;
    int w2 = w >> 2, wj = w & 3;

    // stage A: 16 rows x 1024, f32 -> bf16 (prot read exactly once chip-wide)
    {
        int row = t >> 5, seg = t & 31;
        const float* pr = prot + ((size_t)(b * LL + lc * 16 + row)) * RD + seg * 32;
        unsigned short* dst = aT + row * 1032 + seg * 32;
        #pragma unroll
        for (int c8 = 0; c8 < 4; ++c8) {
            float4 p0 = *(const float4*)(pr + c8 * 8);
            float4 p1 = *(const float4*)(pr + c8 * 8 + 4);
            unsigned short u[8];
            u[0]=f2bf(p0.x); u[1]=f2bf(p0.y); u[2]=f2bf(p0.z); u[3]=f2bf(p0.w);
            u[4]=f2bf(p1.x); u[5]=f2bf(p1.y); u[6]=f2bf(p1.z); u[7]=f2bf(p1.w);
            *(short8*)(dst + c8 * 8) = *(const short8*)u;
        }
    }
    // stage hW1T[b] -> bf16 LDS (independent of A; latency overlaps)
    #pragma unroll
    for (int q = 0; q < 48; ++q) {
        int e = t + 512 * q;                   // 0..24575
        int row = e >> 7, n = e & 127;
        h1[row * 136 + n] = f2bf(hW1T[(size_t)b * HID * NN + e]);
    }
    float v0 = vbuf[wj * 48 + lr];
    float v1 = vbuf[wj * 48 + 16 + lr];
    float v2 = vbuf[wj * 48 + 32 + lr];
    __syncthreads();

    // GEMM: K-half per w2
    f32x4 a0 = {0.f,0.f,0.f,0.f}, a1 = a0, a2 = a0;
    {
        const unsigned short* ap = aT + lr * 1032 + w2 * 512 + lk;
        const unsigned short* bp = WcT + (size_t)(wj * 48 + lr) * RD + w2 * 512 + lk;
        #pragma unroll 4
        for (int k0 = 0; k0 < 512; k0 += 32) {
            short8 av = *(const short8*)(ap + k0);
            short8 b0 = *(const short8*)(bp + k0);
            short8 b1 = *(const short8*)(bp + 16 * RD + k0);
            short8 b2 = *(const short8*)(bp + 32 * RD + k0);
            a0 = MFMA(av, b0, a0, 0, 0, 0);
            a1 = MFMA(av, b1, a1, 0, 0, 0);
            a2 = MFMA(av, b2, a2, 0, 0, 0);
        }
    }
    #pragma unroll
    for (int i = 0; i < 4; ++i) {
        int r = ks * 4 + i;
        pbuf[(w2 * 16 + r) * 192 + wj * 48 + lr]      = a0[i];
        pbuf[(w2 * 16 + r) * 192 + wj * 48 + 16 + lr] = a1[i];
        pbuf[(w2 * 16 + r) * 192 + wj * 48 + 32 + lr] = a2[i];
    }
    __syncthreads();
    float rw0[4], rw1[4], rw2[4];
    #pragma unroll
    for (int i = 0; i < 4; ++i) {
        int r = ks * 4 + i;
        rw0[i] = pbuf[r * 192 + wj*48 + lr]      + pbuf[(16 + r) * 192 + wj*48 + lr];
        rw1[i] = pbuf[r * 192 + wj*48 + 16 + lr] + pbuf[(16 + r) * 192 + wj*48 + 16 + lr];
        rw2[i] = pbuf[r * 192 + wj*48 + 32 + lr] + pbuf[(16 + r) * 192 + wj*48 + 32 + lr];
    }

    // fused pairsum epilogue over n-half w2 (h1 staged pre-barrier)
    const unsigned short* h0p = h1 + (wj * 48 + lr) * 136 + w2 * 64;
    const unsigned short* h1p = h0p + 16 * 136;
    const unsigned short* h2p = h0p + 32 * 136;
    float s = 0.f;
    #pragma unroll 2
    for (int n0 = 0; n0 < 64; n0 += 4) {
        unsigned short e0[4], e1[4], e2[4];
        *(uint2*)e0 = *(const uint2*)(h0p + n0);
        *(uint2*)e1 = *(const uint2*)(h1p + n0);
        *(uint2*)e2 = *(const uint2*)(h2p + n0);
        #pragma unroll
        for (int q = 0; q < 4; ++q) {
            float hh0 = bf2f(e0[q]), hh1 = bf2f(e1[q]), hh2 = bf2f(e2[q]);
            #pragma unroll
            for (int i = 0; i < 4; ++i) {
                s = fmaf(v0, fmaxf(rw0[i] + hh0, 0.f), s);
                s = fmaf(v1, fmaxf(rw1[i] + hh1, 0.f), s);
                s = fmaf(v2, fmaxf(rw2[i] + hh2, 0.f), s);
            }
        }
    }
    for (int off = 32; off; off >>= 1) s += __shfl_down(s, off);
    if (l == 0) sred[w] = s;
    __syncthreads();
    if (t == 0) {
        float tot = ((sred[0] + sred[1]) + (sred[2] + sred[3]))
                  + ((sred[4] + sred[5]) + (sred[6] + sred[7]));
        atomicAdd(&out[b], tot);
    }
}

extern "C" void kernel_launch(void* const* d_in, const int* in_sizes, int n_in,
                              void* d_out, int out_size, void* d_ws, size_t ws_size,
                              hipStream_t stream)
{
    const float* adj   = (const float*)d_in[0];
    const float* nodes = (const float*)d_in[1];
    const float* prot  = (const float*)d_in[2];
    const float* Wn    = (const float*)d_in[3];
    const float* bn    = (const float*)d_in[4];
    const float* Wg    = (const float*)d_in[5];
    const float* bg    = (const float*)d_in[6];
    const float* Wr    = (const float*)d_in[7];
    const float* br    = (const float*)d_in[8];
    // d_in[9]=Wa, d_in[10]=ba: unused (softmax over size-1 axis == 1)
    const float* W1    = (const float*)d_in[11];
    const float* b1    = (const float*)d_in[12];
    const float* W2    = (const float*)d_in[13];
    const float* b2    = (const float*)d_in[14];
    const float* Wo    = (const float*)d_in[15];
    const float* bo    = (const float*)d_in[16];

    float* ws     = (float*)d_ws;
    float* hW1T   = ws;                        // [8][192][128] f32 = 196608
    float* vbuf   = ws + 196608;               // [192]
    unsigned short* WcT = (unsigned short*)(ws + 196800); // [192][1024] bf16
    float* out    = (float*)d_out;

    hipLaunchKernelGGL(k_prep, dim3(25), dim3(512), 0, stream,
                       adj, nodes, Wn, bn, Wr, br, W1, b1, Wg, bg,
                       W2, b2, Wo, bo, WcT, hW1T, vbuf, out);
    hipLaunchKernelGGL(k_gemm, dim3(256), dim3(512), 0, stream,
                       prot, WcT, hW1T, vbuf, out);
}

// Round 14
// 55.180 us; speedup vs baseline: 2.3724x; 1.0216x over previous
//
#include <hip/hip_runtime.h>

#define BB 8
#define NN 128
#define ND 64
#define LL 512
#define RD 1024
#define CG 128
#define HID 192

typedef __attribute__((ext_vector_type(8))) short short8;
typedef __attribute__((ext_vector_type(4))) float f32x4;

__device__ __forceinline__ unsigned short f2bf(float x) {
    unsigned u = __builtin_bit_cast(unsigned, x);
    u += 0x7fffu + ((u >> 16) & 1u);          // RNE
    return (unsigned short)(u >> 16);
}
__device__ __forceinline__ float bf2f(unsigned short h) {
    unsigned u = ((unsigned)h) << 16;
    return __builtin_bit_cast(float, u);
}
#define MFMA __builtin_amdgcn_mfma_f32_16x16x32_bf16

// ---------------------------------------------------------------------------
// K_PREP, grid 25 x 512 (139KB LDS, 1 block/CU; all co-resident):
//  blk 0..15 : WcT[c][k] = bf16((Wr@W1b)[k][c]) via MFMA, 64 k-rows/block.
//  blk 16    : vbuf = W2@Wo ; out[b] = cconst (base for k_gemm atomics)
//  blk 17..24: per-batch GNN, all-MFMA, weights staged once in LDS,
//              norms folded into adjn (regs). Writes hW1b[b][192][128] bf16.
// ---------------------------------------------------------------------------
__global__ __launch_bounds__(512, 1) void k_prep(
    const float* __restrict__ adj, const float* __restrict__ nodes,
    const float* __restrict__ Wn, const float* __restrict__ bn,
    const float* __restrict__ Wr, const float* __restrict__ br,
    const float* __restrict__ W1, const float* __restrict__ b1,
    const float* __restrict__ Wg, const float* __restrict__ bg,
    const float* __restrict__ W2, const float* __restrict__ b2,
    const float* __restrict__ Wo, const float* __restrict__ bo,
    unsigned short* __restrict__ WcT, unsigned short* __restrict__ hW1b,
    float* __restrict__ vbuf, float* __restrict__ out)
{
    __shared__ unsigned short hT[NN][136];    // 34.8KB h (feature-major / node-major)
    __shared__ unsigned short mbuf[NN][72];   // 18.4KB m half / WnT / deg scratch
    __shared__ unsigned short WgT[NN][136];   // 34.8KB WgT[c][j]
    __shared__ unsigned short W1T[HID][136];  // 52.2KB W1T[jj][k] (W1bT in WcT blocks)
    __shared__ float snorm[NN];
    __shared__ float b1cL[HID];
    __shared__ float sbg[NN];
    int t = threadIdx.x, blk = blockIdx.x;
    int w = t >> 6, l = t & 63, lr = l & 15, ks = l >> 4, lk = ks * 8;
    const float* W1b = W1 + CG * HID;

    if (blk < 16) {
        int r0 = blk * 64;
        #pragma unroll
        for (int q = 0; q < 48; ++q) {
            int e = t + 512 * q;              // 0..24575
            int m = e / HID, c = e % HID;
            W1T[c][m] = f2bf(W1[(size_t)(CG + m) * HID + c]);
        }
        int rt = w & 3, jh = w >> 2;
        short8 awr[4];
        #pragma unroll
        for (int kk = 0; kk < 4; ++kk) {
            const float* wp = Wr + (size_t)(r0 + rt * 16 + lr) * CG + kk * 32 + lk;
            float4 q0 = *(const float4*)wp;
            float4 q1 = *(const float4*)(wp + 4);
            unsigned short u[8];
            u[0]=f2bf(q0.x); u[1]=f2bf(q0.y); u[2]=f2bf(q0.z); u[3]=f2bf(q0.w);
            u[4]=f2bf(q1.x); u[5]=f2bf(q1.y); u[6]=f2bf(q1.z); u[7]=f2bf(q1.w);
            awr[kk] = *(const short8*)u;
        }
        __syncthreads();
        #pragma unroll
        for (int jt6 = 0; jt6 < 6; ++jt6) {
            int jt = jh * 6 + jt6;            // 0..11
            f32x4 d = {0.f, 0.f, 0.f, 0.f};
            #pragma unroll
            for (int kk = 0; kk < 4; ++kk) {
                short8 bf = *(const short8*)(&W1T[jt * 16 + lr][kk * 32 + lk]);
                d = MFMA(awr[kk], bf, d, 0, 0, 0);
            }
            unsigned short u[4];
            #pragma unroll
            for (int i = 0; i < 4; ++i) u[i] = f2bf(d[i]);
            *(uint2*)(WcT + (size_t)(jt * 16 + lr) * RD + r0 + rt * 16 + ks * 4) = *(uint2*)u;
        }
        return;
    }
    if (blk == 16) {
        if (t < HID) {
            float s = 0.f;
            #pragma unroll 8
            for (int k = 0; k < CG; ++k) s = fmaf(W2[t * CG + k], Wo[k], s);
            vbuf[t] = s;
        }
        if (t < BB) {
            float s = 0.f;
            for (int k = 0; k < CG; ++k) s = fmaf(b2[k], Wo[k], s);
            out[t] = (float)(NN * LL) * s + bo[0];   // cconst base
        }
        return;
    }

    // ---------------- GNN block, batch b ----------------
    int b = blk - 17;
    int i0 = w * 16;

    // P0: degrees (scratch in mbuf) ; b1c ; stage bg
    {
        float* dscr = (float*)&mbuf[0][0];   // [128][4] f32
        int row = t >> 2, q4 = t & 3;
        const float* ar = adj + ((size_t)b * NN + row) * NN + q4 * 32;
        float d = 0.f;
        #pragma unroll
        for (int c4 = 0; c4 < 8; ++c4) {
            float4 p = *(const float4*)(ar + c4 * 4);
            d += (p.x + p.y) + (p.z + p.w);
        }
        dscr[row * 4 + q4] = d;
        __syncthreads();
        if (t < NN) {
            snorm[t] = rsqrtf(fmaxf(dscr[t*4] + dscr[t*4+1] + dscr[t*4+2] + dscr[t*4+3], 1.f));
        } else if (t < 320) {
            int j = t - 128;
            float s = b1[j];
            #pragma unroll 8
            for (int m = 0; m < CG; ++m)
                s = fmaf(br[m], W1b[(size_t)m * HID + j], s);
            b1cL[j] = s;
        } else if (t < 448) {
            sbg[t - 320] = bg[t - 320];
        }
        __syncthreads();
    }

    // P1: stage WnT (mbuf), WgT, W1T into LDS (coalesced reads)
    unsigned short* WnT = &mbuf[0][0];       // [128][72]
    #pragma unroll
    for (int q = 0; q < 16; ++q) {
        int e = t + 512 * q;
        int c = e & 127, k = e >> 7;
        WnT[c * 72 + k] = f2bf(Wn[(size_t)k * CG + c]);
    }
    #pragma unroll
    for (int q = 0; q < 32; ++q) {
        int e = t + 512 * q;
        int c = e & 127, j = e >> 7;
        WgT[c][j] = f2bf(Wg[(size_t)j * CG + c]);
    }
    #pragma unroll
    for (int q = 0; q < 32; ++q) {
        int e = t + 512 * q;
        int jj = e & 127, k = e >> 7;
        W1T[jj][k] = f2bf(W1[(size_t)k * HID + jj]);
    }
    #pragma unroll
    for (int q = 0; q < 16; ++q) {
        int e = t + 512 * q;
        int jj = 128 + (e & 63), k = e >> 6;
        W1T[jj][k] = f2bf(W1[(size_t)k * HID + jj]);
    }

    // adjn fragments: adjn[i][k] = adj[i][k]*norm[i]*norm[k] (bf16, regs)
    short8 af[4];
    {
        float ni = snorm[i0 + lr];
        const float* ar = adj + ((size_t)b * NN + i0 + lr) * NN;
        #pragma unroll
        for (int kk = 0; kk < 4; ++kk) {
            int kb = kk * 32 + lk;
            float4 p0 = *(const float4*)(ar + kb);
            float4 p1 = *(const float4*)(ar + kb + 4);
            unsigned short u[8];
            u[0] = f2bf(p0.x * ni * snorm[kb+0]); u[1] = f2bf(p0.y * ni * snorm[kb+1]);
            u[2] = f2bf(p0.z * ni * snorm[kb+2]); u[3] = f2bf(p0.w * ni * snorm[kb+3]);
            u[4] = f2bf(p1.x * ni * snorm[kb+4]); u[5] = f2bf(p1.y * ni * snorm[kb+5]);
            u[6] = f2bf(p1.z * ni * snorm[kb+6]); u[7] = f2bf(p1.w * ni * snorm[kb+7]);
            af[kk] = *(const short8*)u;
        }
    }
    short8 bnod[2];
    #pragma unroll
    for (int kk = 0; kk < 2; ++kk) {
        const float* np = nodes + ((size_t)b * NN + i0 + lr) * ND + kk * 32 + lk;
        float4 q0 = *(const float4*)np;
        float4 q1 = *(const float4*)(np + 4);
        unsigned short u[8];
        u[0]=f2bf(q0.x); u[1]=f2bf(q0.y); u[2]=f2bf(q0.z); u[3]=f2bf(q0.w);
        u[4]=f2bf(q1.x); u[5]=f2bf(q1.y); u[6]=f2bf(q1.z); u[7]=f2bf(q1.w);
        bnod[kk] = *(const short8*)u;
    }
    __syncthreads();

    // P2: h0 = nodes@Wn + bn -> hT[c][n] feature-major
    #pragma unroll
    for (int ct = 0; ct < 8; ++ct) {
        f32x4 d = {0.f, 0.f, 0.f, 0.f};
        #pragma unroll
        for (int kk = 0; kk < 2; ++kk) {
            short8 afw = *(const short8*)(WnT + (ct * 16 + lr) * 72 + kk * 32 + lk);
            d = MFMA(afw, bnod[kk], d, 0, 0, 0);
        }
        #pragma unroll
        for (int i = 0; i < 4; ++i)
            hT[ct * 16 + ks * 4 + i][i0 + lr] = f2bf(d[i] + bn[ct * 16 + ks * 4 + i]);
    }
    __syncthreads();

    // P3: 3 GNN steps (ds_read_b128 operands)
    for (int s = 0; s < 3; ++s) {
        f32x4 acc8[8];
        #pragma unroll
        for (int ct = 0; ct < 8; ++ct) acc8[ct] = (f32x4){0.f, 0.f, 0.f, 0.f};
        #pragma unroll
        for (int hf = 0; hf < 2; ++hf) {
            #pragma unroll
            for (int jt = 0; jt < 4; ++jt) {
                int jg = hf * 64 + jt * 16;
                f32x4 d = {0.f, 0.f, 0.f, 0.f};
                #pragma unroll
                for (int kk = 0; kk < 4; ++kk) {
                    short8 bf = *(const short8*)(&hT[jg + lr][kk * 32 + lk]);
                    d = MFMA(af[kk], bf, d, 0, 0, 0);
                }
                #pragma unroll
                for (int i = 0; i < 4; ++i)
                    mbuf[i0 + ks * 4 + i][jt * 16 + lr] = f2bf(d[i]);
            }
            short8 bm[2];
            #pragma unroll
            for (int kk = 0; kk < 2; ++kk)
                bm[kk] = *(const short8*)(&mbuf[i0 + lr][kk * 32 + lk]);
            #pragma unroll
            for (int ct = 0; ct < 8; ++ct) {
                #pragma unroll
                for (int kk = 0; kk < 2; ++kk) {
                    short8 wf = *(const short8*)(&WgT[ct * 16 + lr][hf * 64 + kk * 32 + lk]);
                    if (s < 2)
                        acc8[ct] = MFMA(wf, bm[kk], acc8[ct], 0, 0, 0);
                    else
                        acc8[ct] = MFMA(bm[kk], wf, acc8[ct], 0, 0, 0);
                }
            }
        }
        __syncthreads();
        if (s < 2) {
            #pragma unroll
            for (int ct = 0; ct < 8; ++ct)
                #pragma unroll
                for (int i = 0; i < 4; ++i)
                    hT[ct * 16 + ks * 4 + i][i0 + lr] =
                        f2bf(fmaxf(acc8[ct][i] + sbg[ct * 16 + ks * 4 + i], 0.f));
        } else {
            #pragma unroll
            for (int ct = 0; ct < 8; ++ct)
                #pragma unroll
                for (int i = 0; i < 4; ++i)
                    hT[i0 + ks * 4 + i][ct * 16 + lr] =
                        f2bf(tanhf(acc8[ct][i] + sbg[ct * 16 + lr]));
        }
        __syncthreads();
    }

    // P4: hW1b[jj][n] = bf16(W1topT @ tanh-h + b1c)  (bf16 output - same
    // value the k_gemm epilogue consumed before; conversion just moved here)
    {
        short8 bh[4];
        #pragma unroll
        for (int kk = 0; kk < 4; ++kk)
            bh[kk] = *(const short8*)(&hT[i0 + lr][kk * 32 + lk]);
        #pragma unroll
        for (int jjt = 0; jjt < 12; ++jjt) {
            f32x4 d = {0.f, 0.f, 0.f, 0.f};
            #pragma unroll
            for (int kk = 0; kk < 4; ++kk) {
                short8 wf = *(const short8*)(&W1T[jjt * 16 + lr][kk * 32 + lk]);
                d = MFMA(wf, bh[kk], d, 0, 0, 0);
            }
            #pragma unroll
            for (int i = 0; i < 4; ++i) {
                int jj = jjt * 16 + ks * 4 + i;
                hW1b[(size_t)b * HID * NN + jj * NN + i0 + lr] = f2bf(d[i] + b1cL[jj]);
            }
        }
    }
}

// ---------------------------------------------------------------------------
// K_GEMM, grid 256 x 512 (1 block/CU):
//  block (b, lc): 16 prot rows, all 192 j. A f32->bf16 staged COALESCED in
//  LDS; hW1b (bf16) copied via short8 (no conversion). Wave (w2,wj): K-half
//  w2, 48 j-cols. LDS partial combine; fused pairsum epilogue; ONE
//  atomicAdd(&out[b]) per block (out pre-set to cconst).
// ---------------------------------------------------------------------------
__global__ __launch_bounds__(512, 1) void k_gemm(
    const float* __restrict__ prot, const unsigned short* __restrict__ WcT,
    const unsigned short* __restrict__ hW1b, const float* __restrict__ vbuf,
    float* __restrict__ out)
{
    __shared__ unsigned short aT[16 * 1032];   // 33024B
    __shared__ unsigned short h1[HID * 136];   // 52224B
    __shared__ float pbuf[2 * 16 * 192];       // 24576B
    __shared__ float sred[8];
    int t = threadIdx.x, blk = blockIdx.x;
    int b = blk >> 5, lc = blk & 31;
    int w = t >> 6, l = t & 63, lr = l & 15, ks = l >> 4, lk = ks * 8;
    int w2 = w >> 2, wj = w & 3;

    // stage A: 16 rows x 1024 f32 -> bf16, fully coalesced (lane i -> +32B)
    #pragma unroll
    for (int q = 0; q < 4; ++q) {
        int e = t + 512 * q;                   // 0..2047 units of 8 floats
        int row = e >> 7;                      // 0..15
        int c8 = (e & 127) * 8;                // 0..1016
        const float* pr = prot + ((size_t)(b * LL + lc * 16 + row)) * RD + c8;
        float4 p0 = *(const float4*)pr;
        float4 p1 = *(const float4*)(pr + 4);
        unsigned short u[8];
        u[0]=f2bf(p0.x); u[1]=f2bf(p0.y); u[2]=f2bf(p0.z); u[3]=f2bf(p0.w);
        u[4]=f2bf(p1.x); u[5]=f2bf(p1.y); u[6]=f2bf(p1.z); u[7]=f2bf(p1.w);
        *(short8*)(aT + row * 1032 + c8) = *(const short8*)u;
    }
    // stage hW1b[b] -> LDS: raw bf16 copy, 6 short8 per thread, coalesced
    #pragma unroll
    for (int q = 0; q < 6; ++q) {
        int u8 = t + 512 * q;                  // 0..3071 units of 8 bf16
        int row = u8 >> 4;                     // 0..191
        int n8 = (u8 & 15) * 8;                // 0..120
        short8 v = *(const short8*)(hW1b + (size_t)b * HID * NN + row * NN + n8);
        *(short8*)(h1 + row * 136 + n8) = v;
    }
    float v0 = vbuf[wj * 48 + lr];
    float v1 = vbuf[wj * 48 + 16 + lr];
    float v2 = vbuf[wj * 48 + 32 + lr];
    __syncthreads();

    // GEMM: K-half per w2
    f32x4 a0 = {0.f,0.f,0.f,0.f}, a1 = a0, a2 = a0;
    {
        const unsigned short* ap = aT + lr * 1032 + w2 * 512 + lk;
        const unsigned short* bp = WcT + (size_t)(wj * 48 + lr) * RD + w2 * 512 + lk;
        #pragma unroll 4
        for (int k0 = 0; k0 < 512; k0 += 32) {
            short8 av = *(const short8*)(ap + k0);
            short8 b0 = *(const short8*)(bp + k0);
            short8 b1 = *(const short8*)(bp + 16 * RD + k0);
            short8 b2 = *(const short8*)(bp + 32 * RD + k0);
            a0 = MFMA(av, b0, a0, 0, 0, 0);
            a1 = MFMA(av, b1, a1, 0, 0, 0);
            a2 = MFMA(av, b2, a2, 0, 0, 0);
        }
    }
    #pragma unroll
    for (int i = 0; i < 4; ++i) {
        int r = ks * 4 + i;
        pbuf[(w2 * 16 + r) * 192 + wj * 48 + lr]      = a0[i];
        pbuf[(w2 * 16 + r) * 192 + wj * 48 + 16 + lr] = a1[i];
        pbuf[(w2 * 16 + r) * 192 + wj * 48 + 32 + lr] = a2[i];
    }
    __syncthreads();
    float rw0[4], rw1[4], rw2[4];
    #pragma unroll
    for (int i = 0; i < 4; ++i) {
        int r = ks * 4 + i;
        rw0[i] = pbuf[r * 192 + wj*48 + lr]      + pbuf[(16 + r) * 192 + wj*48 + lr];
        rw1[i] = pbuf[r * 192 + wj*48 + 16 + lr] + pbuf[(16 + r) * 192 + wj*48 + 16 + lr];
        rw2[i] = pbuf[r * 192 + wj*48 + 32 + lr] + pbuf[(16 + r) * 192 + wj*48 + 32 + lr];
    }

    // fused pairsum epilogue over n-half w2
    const unsigned short* h0p = h1 + (wj * 48 + lr) * 136 + w2 * 64;
    const unsigned short* h1p = h0p + 16 * 136;
    const unsigned short* h2p = h0p + 32 * 136;
    float s = 0.f;
    #pragma unroll 2
    for (int n0 = 0; n0 < 64; n0 += 4) {
        unsigned short e0[4], e1[4], e2[4];
        *(uint2*)e0 = *(const uint2*)(h0p + n0);
        *(uint2*)e1 = *(const uint2*)(h1p + n0);
        *(uint2*)e2 = *(const uint2*)(h2p + n0);
        #pragma unroll
        for (int q = 0; q < 4; ++q) {
            float hh0 = bf2f(e0[q]), hh1 = bf2f(e1[q]), hh2 = bf2f(e2[q]);
            #pragma unroll
            for (int i = 0; i < 4; ++i) {
                s = fmaf(v0, fmaxf(rw0[i] + hh0, 0.f), s);
                s = fmaf(v1, fmaxf(rw1[i] + hh1, 0.f), s);
                s = fmaf(v2, fmaxf(rw2[i] + hh2, 0.f), s);
            }
        }
    }
    for (int off = 32; off; off >>= 1) s += __shfl_down(s, off);
    if (l == 0) sred[w] = s;
    __syncthreads();
    if (t == 0) {
        float tot = ((sred[0] + sred[1]) + (sred[2] + sred[3]))
                  + ((sred[4] + sred[5]) + (sred[6] + sred[7]));
        atomicAdd(&out[b], tot);
    }
}

extern "C" void kernel_launch(void* const* d_in, const int* in_sizes, int n_in,
                              void* d_out, int out_size, void* d_ws, size_t ws_size,
                              hipStream_t stream)
{
    const float* adj   = (const float*)d_in[0];
    const float* nodes = (const float*)d_in[1];
    const float* prot  = (const float*)d_in[2];
    const float* Wn    = (const float*)d_in[3];
    const float* bn    = (const float*)d_in[4];
    const float* Wg    = (const float*)d_in[5];
    const float* bg    = (const float*)d_in[6];
    const float* Wr    = (const float*)d_in[7];
    const float* br    = (const float*)d_in[8];
    // d_in[9]=Wa, d_in[10]=ba: unused (softmax over size-1 axis == 1)
    const float* W1    = (const float*)d_in[11];
    const float* b1    = (const float*)d_in[12];
    const float* W2    = (const float*)d_in[13];
    const float* b2    = (const float*)d_in[14];
    const float* Wo    = (const float*)d_in[15];
    const float* bo    = (const float*)d_in[16];

    float* ws     = (float*)d_ws;
    float* vbuf   = ws;                                   // [192]
    unsigned short* hW1b = (unsigned short*)(ws + 192);   // [8][192][128] bf16
    unsigned short* WcT  = hW1b + (size_t)BB * HID * NN;  // [192][1024] bf16
    float* out    = (float*)d_out;

    hipLaunchKernelGGL(k_prep, dim3(25), dim3(512), 0, stream,
                       adj, nodes, Wn, bn, Wr, br, W1, b1, Wg, bg,
                       W2, b2, Wo, bo, WcT, hW1b, vbuf, out);
    hipLaunchKernelGGL(k_gemm, dim3(256), dim3(512), 0, stream,
                       prot, WcT, hW1b, vbuf, out);
}